// Round 1
// baseline (1045.312 us; speedup 1.0000x reference)
//
#include <hip/hip_runtime.h>
#include <math.h>

#define BATCH 8
#define SEQ   2048
#define CH    256
#define NH    4
#define HD    64
#define SCALE 0.125f   // 64^-0.5

// ---------------------------------------------------------------------------
// GEMM with bias: O[M,N] = A[M,K] @ W[K,N] + bias[N]
// 64x64 block tile, TK=16, 256 threads, 4x4 register micro-tile per thread.
// M,N,K all multiples of 64/64/16 for our shapes (no bounds checks).
// ---------------------------------------------------------------------------
__global__ __launch_bounds__(256) void gemm_bias_kernel(
    const float* __restrict__ A, const float* __restrict__ W,
    const float* __restrict__ bias, float* __restrict__ O,
    int M, int N, int K) {
    __shared__ float As[16][64];   // transposed A tile: As[k][m]
    __shared__ float Ws[16][64];   // Ws[k][n]

    const int tid = threadIdx.x;
    const int m0 = blockIdx.y * 64;
    const int n0 = blockIdx.x * 64;
    const int tr = tid >> 4;       // 0..15 -> rows tr*4..tr*4+3
    const int tc = tid & 15;       // 0..15 -> cols tc*4..tc*4+3

    float acc[4][4] = {};

    for (int k0 = 0; k0 < K; k0 += 16) {
        // A tile: 64 rows x 16 k. One float4 per thread.
        {
            const int row = tid >> 2;            // 0..63
            const int kq  = (tid & 3) * 4;       // 0,4,8,12
            const float4 av = *(const float4*)&A[(m0 + row) * K + k0 + kq];
            As[kq + 0][row] = av.x;
            As[kq + 1][row] = av.y;
            As[kq + 2][row] = av.z;
            As[kq + 3][row] = av.w;
        }
        // W tile: 16 rows x 64 cols. One float4 per thread.
        {
            const int row = tid >> 4;            // 0..15
            const int cq  = (tid & 15) * 4;      // 0..60
            *(float4*)&Ws[row][cq] = *(const float4*)&W[(k0 + row) * N + n0 + cq];
        }
        __syncthreads();
        #pragma unroll
        for (int kk = 0; kk < 16; kk++) {
            const float4 a = *(const float4*)&As[kk][tr * 4];
            const float4 b = *(const float4*)&Ws[kk][tc * 4];
            const float av[4] = {a.x, a.y, a.z, a.w};
            const float bv[4] = {b.x, b.y, b.z, b.w};
            #pragma unroll
            for (int i = 0; i < 4; i++)
                #pragma unroll
                for (int j = 0; j < 4; j++)
                    acc[i][j] += av[i] * bv[j];
        }
        __syncthreads();
    }

    const float4 bv = *(const float4*)&bias[n0 + tc * 4];
    #pragma unroll
    for (int i = 0; i < 4; i++) {
        float4 o;
        o.x = acc[i][0] + bv.x;
        o.y = acc[i][1] + bv.y;
        o.z = acc[i][2] + bv.z;
        o.w = acc[i][3] + bv.w;
        *(float4*)&O[(m0 + tr * 4 + i) * N + n0 + tc * 4] = o;
    }
}

// ---------------------------------------------------------------------------
// Causal flash-style attention, fp32.
// qkv: (B, T, 3*C) where element (b,t, m*C + h*64 + d) is {q,k,v}[m][b][h][t][d]
// out: (B, T, C)   out[b][t][h*64+d]  (already in (B,T,H,D) concat layout)
// Block: 256 threads handles one (b, h, 32-query tile). Iterates 32-key tiles.
// ---------------------------------------------------------------------------
#define BQ 32
#define BK 32
#define KP 68   // padded LDS row stride (16B-aligned, bank-shifts rows by 4)

__global__ __launch_bounds__(256) void attn_kernel(
    const float* __restrict__ qkv, float* __restrict__ out) {
    __shared__ float Qs[BQ][KP];
    __shared__ float Ks[BK][KP];
    __shared__ float Vs[BK][KP];
    __shared__ float Ss[BQ][BK + 1];
    __shared__ float m_s[BQ], l_s[BQ], alpha_s[BQ];

    const int qt  = blockIdx.x;            // query tile index, 0..T/BQ-1
    const int bh  = blockIdx.y;            // 0..B*H-1
    const int b   = bh / NH;
    const int h   = bh % NH;
    const int tid = threadIdx.x;

    const int base = b * SEQ * (3 * CH);   // fits in int (max ~12.6M)

    // Load Q tile: 32 rows x 64 floats = 512 float4, 2 per thread.
    #pragma unroll
    for (int r = 0; r < 2; r++) {
        const int fid = tid + r * 256;
        const int row = fid >> 4;          // 0..31
        const int c4  = (fid & 15) * 4;    // 0..60
        *(float4*)&Qs[row][c4] =
            *(const float4*)&qkv[base + (qt * BQ + row) * (3 * CH) + h * HD + c4];
    }
    if (tid < BQ) { m_s[tid] = -INFINITY; l_s[tid] = 0.0f; }

    // S-compute assignment: si = tid/8 (row), j in {tid%8 + 8*jj}
    const int si    = tid >> 3;
    const int jbase = tid & 7;
    // O-accumulator assignment: row = tid/8, cols (tid%8)*8 .. +7
    const int orow = tid >> 3;
    const int ocol = (tid & 7) * 8;
    float o_acc[8] = {0, 0, 0, 0, 0, 0, 0, 0};

    __syncthreads();

    for (int kt = 0; kt <= qt; kt++) {
        // Load K and V tiles (each 512 float4, 2 per thread).
        #pragma unroll
        for (int r = 0; r < 2; r++) {
            const int fid = tid + r * 256;
            const int row = fid >> 4;
            const int c4  = (fid & 15) * 4;
            const int rb  = base + (kt * BK + row) * (3 * CH) + h * HD + c4;
            *(float4*)&Ks[row][c4] = *(const float4*)&qkv[rb + CH];
            *(float4*)&Vs[row][c4] = *(const float4*)&qkv[rb + 2 * CH];
        }
        __syncthreads();

        // S = Q K^T * SCALE (+ causal mask), each thread 4 elements of 32x32.
        float s_acc[4] = {0, 0, 0, 0};
        #pragma unroll 4
        for (int d4 = 0; d4 < 16; d4++) {
            const float4 qv = *(const float4*)&Qs[si][d4 * 4];
            #pragma unroll
            for (int jj = 0; jj < 4; jj++) {
                const float4 kv = *(const float4*)&Ks[jbase + 8 * jj][d4 * 4];
                s_acc[jj] += qv.x * kv.x + qv.y * kv.y + qv.z * kv.z + qv.w * kv.w;
            }
        }
        const int qg = qt * BQ + si;
        #pragma unroll
        for (int jj = 0; jj < 4; jj++) {
            const int j  = jbase + 8 * jj;
            const int kg = kt * BK + j;
            Ss[si][j] = (kg > qg) ? -INFINITY : s_acc[jj] * SCALE;
        }
        __syncthreads();

        // Online softmax per row (threads 0..31, one row each).
        if (tid < BQ) {
            const float m_old = m_s[tid];
            float mx = m_old;
            #pragma unroll 8
            for (int j = 0; j < BK; j++) mx = fmaxf(mx, Ss[tid][j]);
            const float alpha = __expf(m_old - mx);
            float l = l_s[tid] * alpha;
            #pragma unroll 8
            for (int j = 0; j < BK; j++) {
                const float p = __expf(Ss[tid][j] - mx);
                Ss[tid][j] = p;
                l += p;
            }
            m_s[tid] = mx;
            l_s[tid] = l;
            alpha_s[tid] = alpha;
        }
        __syncthreads();

        // O = O*alpha + P @ V
        const float alpha = alpha_s[orow];
        #pragma unroll
        for (int c = 0; c < 8; c++) o_acc[c] *= alpha;
        #pragma unroll 8
        for (int j = 0; j < BK; j++) {
            const float p = Ss[orow][j];
            const float4 v0 = *(const float4*)&Vs[j][ocol];
            const float4 v1 = *(const float4*)&Vs[j][ocol + 4];
            o_acc[0] += p * v0.x; o_acc[1] += p * v0.y;
            o_acc[2] += p * v0.z; o_acc[3] += p * v0.w;
            o_acc[4] += p * v1.x; o_acc[5] += p * v1.y;
            o_acc[6] += p * v1.z; o_acc[7] += p * v1.w;
        }
        __syncthreads();   // protect Ks/Vs/Ss before next iteration's writes
    }

    // Normalize and store: out[b][t][h*64 + d]
    const float linv = 1.0f / l_s[orow];
    const int   t    = qt * BQ + orow;
    float4 r0, r1;
    r0.x = o_acc[0] * linv; r0.y = o_acc[1] * linv;
    r0.z = o_acc[2] * linv; r0.w = o_acc[3] * linv;
    r1.x = o_acc[4] * linv; r1.y = o_acc[5] * linv;
    r1.z = o_acc[6] * linv; r1.w = o_acc[7] * linv;
    float* op = &out[(b * SEQ + t) * CH + h * HD + ocol];
    *(float4*)op       = r0;
    *(float4*)(op + 4) = r1;
}

extern "C" void kernel_launch(void* const* d_in, const int* in_sizes, int n_in,
                              void* d_out, int out_size, void* d_ws, size_t ws_size,
                              hipStream_t stream) {
    const float* x     = (const float*)d_in[0];
    const float* Wqkv  = (const float*)d_in[1];
    const float* bqkv  = (const float*)d_in[2];
    const float* Wproj = (const float*)d_in[3];
    const float* bproj = (const float*)d_in[4];
    float* out = (float*)d_out;

    float* qkv_ws  = (float*)d_ws;                                  // B*T*3C floats
    float* attn_ws = qkv_ws + (size_t)BATCH * SEQ * 3 * CH;          // B*T*C floats

    const int M = BATCH * SEQ;   // 16384

    // 1) QKV projection: (M x 256) @ (256 x 768) + bias
    {
        dim3 grid((3 * CH) / 64, M / 64);
        gemm_bias_kernel<<<grid, 256, 0, stream>>>(x, Wqkv, bqkv, qkv_ws, M, 3 * CH, CH);
    }
    // 2) Causal attention
    {
        dim3 grid(SEQ / BQ, BATCH * NH);
        attn_kernel<<<grid, 256, 0, stream>>>(qkv_ws, attn_ws);
    }
    // 3) Output projection: (M x 256) @ (256 x 256) + bias
    {
        dim3 grid(CH / 64, M / 64);
        gemm_bias_kernel<<<grid, 256, 0, stream>>>(attn_ws, Wproj, bproj, out, M, CH, CH);
    }
}

// Round 2
// 272.811 us; speedup vs baseline: 3.8316x; 3.8316x over previous
//
#include <hip/hip_runtime.h>
#include <math.h>

#define BATCH 8
#define SEQ   2048
#define CH    256
#define NH    4
#define HD    64
#define NQB   (SEQ / 64)      // 32 query tiles of 64
#define SCALE 0.125f          // 64^-0.5

typedef short  bfrag __attribute__((ext_vector_type(8)));  // 8 bf16 (4 VGPRs)
typedef float  ffrag __attribute__((ext_vector_type(4)));  // 4 fp32 acc

__device__ __forceinline__ unsigned short f2bf(float f) {
    union { float f; unsigned int u; } v; v.f = f;
    unsigned int r = v.u + 0x7FFF + ((v.u >> 16) & 1);   // RNE
    return (unsigned short)(r >> 16);
}

// ---------------------------------------------------------------------------
// QKV GEMM: x(16384x256) @ Wqkv(256x768) + bqkv, epilogue writes bf16:
//   Q,K -> [B*H][T][D] row-major;  V -> transposed [B*H][D][T].
// 64x64 tile, 256 threads, 4x4 micro-tile. mat & head are block-uniform.
// ---------------------------------------------------------------------------
__global__ __launch_bounds__(256) void qkv_gemm_kernel(
    const float* __restrict__ A, const float* __restrict__ W,
    const float* __restrict__ bias,
    unsigned short* __restrict__ Qb, unsigned short* __restrict__ Kb,
    unsigned short* __restrict__ Vtb) {
    const int M = BATCH * SEQ, N = 3 * CH, K = CH;
    __shared__ float As[16][64];
    __shared__ float Ws[16][64];

    const int tid = threadIdx.x;
    const int m0 = blockIdx.y * 64;
    const int n0b = blockIdx.x * 64;
    const int tr = tid >> 4;
    const int tc = tid & 15;

    float acc[4][4] = {};

    for (int k0 = 0; k0 < K; k0 += 16) {
        {
            const int row = tid >> 2;
            const int kq  = (tid & 3) * 4;
            const float4 av = *(const float4*)&A[(m0 + row) * K + k0 + kq];
            As[kq + 0][row] = av.x; As[kq + 1][row] = av.y;
            As[kq + 2][row] = av.z; As[kq + 3][row] = av.w;
        }
        {
            const int row = tid >> 4;
            const int cq  = (tid & 15) * 4;
            *(float4*)&Ws[row][cq] = *(const float4*)&W[(k0 + row) * N + n0b + cq];
        }
        __syncthreads();
        #pragma unroll
        for (int kk = 0; kk < 16; kk++) {
            const float4 a = *(const float4*)&As[kk][tr * 4];
            const float4 b = *(const float4*)&Ws[kk][tc * 4];
            const float av[4] = {a.x, a.y, a.z, a.w};
            const float bv[4] = {b.x, b.y, b.z, b.w};
            #pragma unroll
            for (int i = 0; i < 4; i++)
                #pragma unroll
                for (int j = 0; j < 4; j++)
                    acc[i][j] += av[i] * bv[j];
        }
        __syncthreads();
    }

    const int n0  = n0b + tc * 4;
    const int mat = n0 >> 8;           // 0=Q 1=K 2=V (block-uniform)
    const int h   = (n0 >> 6) & 3;     // block-uniform
    const int d0  = n0 & 63;
    const int b   = m0 >> 11;          // SEQ=2048
    const int bh  = b * NH + h;
    const int tl0 = (m0 & (SEQ - 1)) + tr * 4;
    const float4 bv = *(const float4*)&bias[n0];
    const float bias4[4] = {bv.x, bv.y, bv.z, bv.w};

    if (mat < 2) {
        unsigned short* dst = (mat == 0) ? Qb : Kb;
        #pragma unroll
        for (int i = 0; i < 4; i++) {
            ushort4 pk;
            pk.x = f2bf(acc[i][0] + bias4[0]);
            pk.y = f2bf(acc[i][1] + bias4[1]);
            pk.z = f2bf(acc[i][2] + bias4[2]);
            pk.w = f2bf(acc[i][3] + bias4[3]);
            *(ushort4*)&dst[(bh * SEQ + tl0 + i) * HD + d0] = pk;
        }
    } else {
        #pragma unroll
        for (int j = 0; j < 4; j++) {
            ushort4 pk;
            pk.x = f2bf(acc[0][j] + bias4[j]);
            pk.y = f2bf(acc[1][j] + bias4[j]);
            pk.z = f2bf(acc[2][j] + bias4[j]);
            pk.w = f2bf(acc[3][j] + bias4[j]);
            *(ushort4*)&Vtb[(bh * HD + d0 + j) * SEQ + tl0] = pk;
        }
    }
}

// ---------------------------------------------------------------------------
// MFMA flash attention (causal), bf16 inputs, fp32 accum.
// Block = 256 threads = 4 waves, BQ=64 (wave w owns q-rows 16w..16w+15),
// BK=64 per iteration. Block x handles q-tiles {x, 31-x}: uniform 33 iters.
// LDS rows padded to 72 bf16 (144 B = 16B-aligned, rows step 4 banks).
// ---------------------------------------------------------------------------
#define LS 72

__global__ __launch_bounds__(256) void attn_mfma_kernel(
    const unsigned short* __restrict__ Qb, const unsigned short* __restrict__ Kb,
    const unsigned short* __restrict__ Vtb, float* __restrict__ out) {
    __shared__ unsigned short Qs[64][LS];
    __shared__ unsigned short Ks[64][LS];
    __shared__ unsigned short Vts[64][LS];
    __shared__ unsigned short Ps[64][LS];

    const int tid = threadIdx.x;
    const int wv  = tid >> 6;         // wave 0..3
    const int ln  = tid & 63;
    const int l15 = ln & 15;
    const int l4  = ln >> 4;          // quad 0..3
    const int bh  = blockIdx.y;
    const int b   = bh >> 2;          // NH=4
    const int h   = bh & 3;

    for (int rep = 0; rep < 2; rep++) {
        const int qb = (rep == 0) ? (int)blockIdx.x : (NQB - 1 - (int)blockIdx.x);

        // ---- stage Q tile (64x64 bf16) ----
        {
            const unsigned short* Qp = Qb + (size_t)(bh * SEQ + qb * 64) * HD;
            #pragma unroll
            for (int r = 0; r < 2; r++) {
                const int fid = tid + r * 256;
                const int row = fid >> 3, c8 = (fid & 7) * 8;
                *(uint4*)&Qs[row][c8] = *(const uint4*)&Qp[row * HD + c8];
            }
        }
        __syncthreads();
        const bfrag aq0 = *(const bfrag*)&Qs[wv * 16 + l15][l4 * 8];
        const bfrag aq1 = *(const bfrag*)&Qs[wv * 16 + l15][32 + l4 * 8];

        ffrag o[4];
        #pragma unroll
        for (int n = 0; n < 4; n++) o[n] = (ffrag){0.f, 0.f, 0.f, 0.f};
        float m_r[4] = {-INFINITY, -INFINITY, -INFINITY, -INFINITY};
        float l_r[4] = {0.f, 0.f, 0.f, 0.f};

        for (int kt = 0; kt <= qb; kt++) {
            // ---- stage K tile + V^T tile ----
            {
                const unsigned short* Kp  = Kb  + (size_t)(bh * SEQ + kt * 64) * HD;
                const unsigned short* Vtp = Vtb + (size_t)(bh * HD) * SEQ + kt * 64;
                #pragma unroll
                for (int r = 0; r < 2; r++) {
                    const int fid = tid + r * 256;
                    const int row = fid >> 3, c8 = (fid & 7) * 8;
                    *(uint4*)&Ks[row][c8]  = *(const uint4*)&Kp[row * HD + c8];
                    *(uint4*)&Vts[row][c8] = *(const uint4*)&Vtp[row * SEQ + c8];
                }
            }
            __syncthreads();

            // ---- S = Q K^T * SCALE  (4 col-tiles x 2 k-chunks) ----
            ffrag s[4];
            #pragma unroll
            for (int n = 0; n < 4; n++) {
                const bfrag bk0 = *(const bfrag*)&Ks[n * 16 + l15][l4 * 8];
                const bfrag bk1 = *(const bfrag*)&Ks[n * 16 + l15][32 + l4 * 8];
                ffrag z = (ffrag){0.f, 0.f, 0.f, 0.f};
                z = __builtin_amdgcn_mfma_f32_16x16x32_bf16(aq0, bk0, z, 0, 0, 0);
                z = __builtin_amdgcn_mfma_f32_16x16x32_bf16(aq1, bk1, z, 0, 0, 0);
                #pragma unroll
                for (int r = 0; r < 4; r++) z[r] *= SCALE;
                s[n] = z;
            }
            // causal mask (only the diagonal block)
            if (kt == qb) {
                #pragma unroll
                for (int n = 0; n < 4; n++)
                    #pragma unroll
                    for (int r = 0; r < 4; r++)
                        if (n * 16 + l15 > wv * 16 + l4 * 4 + r) s[n][r] = -INFINITY;
            }

            // ---- online softmax (per-wave rows; reduce over 16 lanes) ----
            float alpha[4], rowsum[4] = {0.f, 0.f, 0.f, 0.f};
            #pragma unroll
            for (int r = 0; r < 4; r++) {
                float mx = fmaxf(fmaxf(s[0][r], s[1][r]), fmaxf(s[2][r], s[3][r]));
                #pragma unroll
                for (int off = 1; off < 16; off <<= 1)
                    mx = fmaxf(mx, __shfl_xor(mx, off));
                const float mo = m_r[r];
                const float mn = fmaxf(mo, mx);
                alpha[r] = __expf(mo - mn);
                m_r[r]   = mn;
            }
            #pragma unroll
            for (int n = 0; n < 4; n++)
                #pragma unroll
                for (int r = 0; r < 4; r++) {
                    const float p = __expf(s[n][r] - m_r[r]);
                    s[n][r] = p;
                    rowsum[r] += p;
                }
            #pragma unroll
            for (int r = 0; r < 4; r++) {
                float rs = rowsum[r];
                #pragma unroll
                for (int off = 1; off < 16; off <<= 1)
                    rs += __shfl_xor(rs, off);
                l_r[r] = l_r[r] * alpha[r] + rs;
            }
            #pragma unroll
            for (int n = 0; n < 4; n++)
                #pragma unroll
                for (int r = 0; r < 4; r++) o[n][r] *= alpha[r];

            // ---- P -> bf16 via per-wave-private LDS rows (C-layout -> A-layout)
            #pragma unroll
            for (int n = 0; n < 4; n++)
                #pragma unroll
                for (int r = 0; r < 4; r++)
                    Ps[wv * 16 + l4 * 4 + r][n * 16 + l15] = f2bf(s[n][r]);
            const bfrag ap0 = *(const bfrag*)&Ps[wv * 16 + l15][l4 * 8];
            const bfrag ap1 = *(const bfrag*)&Ps[wv * 16 + l15][32 + l4 * 8];

            // ---- O += P @ V  (V^T staged: B[k=ks][n=d] = Vts[d][ks]) ----
            #pragma unroll
            for (int n = 0; n < 4; n++) {
                const bfrag bv0 = *(const bfrag*)&Vts[n * 16 + l15][l4 * 8];
                const bfrag bv1 = *(const bfrag*)&Vts[n * 16 + l15][32 + l4 * 8];
                o[n] = __builtin_amdgcn_mfma_f32_16x16x32_bf16(ap0, bv0, o[n], 0, 0, 0);
                o[n] = __builtin_amdgcn_mfma_f32_16x16x32_bf16(ap1, bv1, o[n], 0, 0, 0);
            }
            __syncthreads();   // protect Ks/Vts before next staging
        }

        // ---- normalize + store O (fp32, [B,T,C] with C = h*64+d) ----
        float linv[4];
        #pragma unroll
        for (int r = 0; r < 4; r++) linv[r] = 1.0f / l_r[r];
        const int tg = qb * 64 + wv * 16 + l4 * 4;
        float* op = out + (size_t)(b * SEQ) * CH + h * HD;
        #pragma unroll
        for (int n = 0; n < 4; n++)
            #pragma unroll
            for (int r = 0; r < 4; r++)
                op[(size_t)(tg + r) * CH + n * 16 + l15] = o[n][r] * linv[r];
    }
}

// ---------------------------------------------------------------------------
// Output projection (fp32): attn(16384x256) @ Wproj(256x256) + bproj
// ---------------------------------------------------------------------------
__global__ __launch_bounds__(256) void gemm_bias_kernel(
    const float* __restrict__ A, const float* __restrict__ W,
    const float* __restrict__ bias, float* __restrict__ O,
    int M, int N, int K) {
    __shared__ float As[16][64];
    __shared__ float Ws[16][64];

    const int tid = threadIdx.x;
    const int m0 = blockIdx.y * 64;
    const int n0 = blockIdx.x * 64;
    const int tr = tid >> 4;
    const int tc = tid & 15;

    float acc[4][4] = {};

    for (int k0 = 0; k0 < K; k0 += 16) {
        {
            const int row = tid >> 2;
            const int kq  = (tid & 3) * 4;
            const float4 av = *(const float4*)&A[(m0 + row) * K + k0 + kq];
            As[kq + 0][row] = av.x; As[kq + 1][row] = av.y;
            As[kq + 2][row] = av.z; As[kq + 3][row] = av.w;
        }
        {
            const int row = tid >> 4;
            const int cq  = (tid & 15) * 4;
            *(float4*)&Ws[row][cq] = *(const float4*)&W[(k0 + row) * N + n0 + cq];
        }
        __syncthreads();
        #pragma unroll
        for (int kk = 0; kk < 16; kk++) {
            const float4 a = *(const float4*)&As[kk][tr * 4];
            const float4 b = *(const float4*)&Ws[kk][tc * 4];
            const float av[4] = {a.x, a.y, a.z, a.w};
            const float bv[4] = {b.x, b.y, b.z, b.w};
            #pragma unroll
            for (int i = 0; i < 4; i++)
                #pragma unroll
                for (int j = 0; j < 4; j++)
                    acc[i][j] += av[i] * bv[j];
        }
        __syncthreads();
    }

    const float4 bv = *(const float4*)&bias[n0 + tc * 4];
    #pragma unroll
    for (int i = 0; i < 4; i++) {
        float4 o;
        o.x = acc[i][0] + bv.x;
        o.y = acc[i][1] + bv.y;
        o.z = acc[i][2] + bv.z;
        o.w = acc[i][3] + bv.w;
        *(float4*)&O[(m0 + tr * 4 + i) * N + n0 + tc * 4] = o;
    }
}

extern "C" void kernel_launch(void* const* d_in, const int* in_sizes, int n_in,
                              void* d_out, int out_size, void* d_ws, size_t ws_size,
                              hipStream_t stream) {
    const float* x     = (const float*)d_in[0];
    const float* Wqkv  = (const float*)d_in[1];
    const float* bqkv  = (const float*)d_in[2];
    const float* Wproj = (const float*)d_in[3];
    const float* bproj = (const float*)d_in[4];
    float* out = (float*)d_out;

    const size_t BHTD = (size_t)BATCH * NH * SEQ * HD;   // 4,194,304
    unsigned short* Qb  = (unsigned short*)d_ws;
    unsigned short* Kb  = Qb + BHTD;
    unsigned short* Vtb = Kb + BHTD;
    float* attn_ws = (float*)(Vtb + BHTD);               // 16384*256 fp32

    const int M = BATCH * SEQ;   // 16384

    // 1) QKV projection -> bf16 Q/K ([BH,T,D]) + V^T ([BH,D,T])
    {
        dim3 grid((3 * CH) / 64, M / 64);
        qkv_gemm_kernel<<<grid, 256, 0, stream>>>(x, Wqkv, bqkv, Qb, Kb, Vtb);
    }
    // 2) Causal MFMA flash attention
    {
        dim3 grid(NQB / 2, BATCH * NH);
        attn_mfma_kernel<<<grid, 256, 0, stream>>>(Qb, Kb, Vtb, attn_ws);
    }
    // 3) Output projection (fp32)
    {
        dim3 grid(CH / 64, M / 64);
        gemm_bias_kernel<<<grid, 256, 0, stream>>>(attn_ws, Wproj, bproj, out, M, CH, CH);
    }
}

// Round 3
// 178.898 us; speedup vs baseline: 5.8430x; 1.5249x over previous
//
#include <hip/hip_runtime.h>
#include <math.h>

#define BATCH 8
#define SEQ   2048
#define CH    256
#define NH    4
#define HD    64
#define NQB   (SEQ / 64)      // 32 query tiles of 64
#define SCALE 0.125f          // 64^-0.5

typedef short  bfrag __attribute__((ext_vector_type(8)));  // 8 bf16 (4 VGPRs)
typedef float  ffrag __attribute__((ext_vector_type(4)));  // 4 fp32 acc
typedef unsigned short ushort_t;

__device__ __forceinline__ unsigned short f2bf(float f) {
    union { float f; unsigned int u; } v; v.f = f;
    unsigned int r = v.u + 0x7FFF + ((v.u >> 16) & 1);   // RNE
    return (unsigned short)(r >> 16);
}

// ---------------------------------------------------------------------------
// Prep: x -> bf16; Wqkv, Wproj -> transposed bf16 (W^T[n][k]).
// ---------------------------------------------------------------------------
#define XN  (BATCH * SEQ * CH / 4)   // 1048576 float4 groups
#define WQN (CH * 3 * CH)            // 196608
#define WPN (CH * CH)                // 65536

__global__ __launch_bounds__(256) void prep_kernel(
    const float* __restrict__ x, const float* __restrict__ Wqkv,
    const float* __restrict__ Wproj,
    ushort_t* __restrict__ xb, ushort_t* __restrict__ WqkvT,
    ushort_t* __restrict__ WprojT) {
    const int fid = blockIdx.x * 256 + threadIdx.x;
    if (fid < XN) {
        const float4 v = ((const float4*)x)[fid];
        ushort4 p;
        p.x = f2bf(v.x); p.y = f2bf(v.y); p.z = f2bf(v.z); p.w = f2bf(v.w);
        ((ushort4*)xb)[fid] = p;
    } else if (fid < XN + WQN) {
        const int i = fid - XN;
        const int n = i >> 8, k = i & 255;
        WqkvT[n * CH + k] = f2bf(Wqkv[k * (3 * CH) + n]);
    } else if (fid < XN + WQN + WPN) {
        const int i = fid - XN - WQN;
        const int n = i >> 8, k = i & 255;
        WprojT[n * CH + k] = f2bf(Wproj[k * CH + n]);
    }
}

// ---------------------------------------------------------------------------
// QKV MFMA GEMM: xb(16384x256) @ WqkvT^T + bqkv -> bf16 Q,K [BH,T,D], V^T [BH,D,T].
// 128x128 block tile, 4 waves each 64x64, BK=64 (2 mfma-K chunks of 32).
// ---------------------------------------------------------------------------
#define GLS 72   // LDS row stride in ushorts (144 B, 16B-aligned)

__global__ __launch_bounds__(256) void qkv_mfma_kernel(
    const ushort_t* __restrict__ xb, const ushort_t* __restrict__ Wt,
    const float* __restrict__ bias,
    ushort_t* __restrict__ Qb, ushort_t* __restrict__ Kb,
    ushort_t* __restrict__ Vtb) {
    __shared__ ushort_t smem[2 * 128 * GLS];   // As | Bs; reused as T[128][136]
    ushort_t* As = smem;
    ushort_t* Bs = smem + 128 * GLS;

    const int tid = threadIdx.x;
    const int wv  = tid >> 6;
    const int ln  = tid & 63;
    const int l15 = ln & 15;
    const int l4  = ln >> 4;
    const int wr  = wv >> 1;          // wave row 0..1
    const int wc  = wv & 1;           // wave col 0..1
    const int n0  = blockIdx.x * 128;
    const int m0  = blockIdx.y * 128;

    ffrag acc[4][4];
    #pragma unroll
    for (int i = 0; i < 4; i++)
        #pragma unroll
        for (int j = 0; j < 4; j++) acc[i][j] = (ffrag){0.f, 0.f, 0.f, 0.f};

    for (int k0 = 0; k0 < CH; k0 += 64) {
        #pragma unroll
        for (int r = 0; r < 4; r++) {
            const int fid = tid + r * 256;
            const int row = fid >> 3, c8 = (fid & 7) * 8;
            *(uint4*)&As[row * GLS + c8] = *(const uint4*)&xb[(m0 + row) * CH + k0 + c8];
            *(uint4*)&Bs[row * GLS + c8] = *(const uint4*)&Wt[(n0 + row) * CH + k0 + c8];
        }
        __syncthreads();
        #pragma unroll
        for (int kk = 0; kk < 64; kk += 32) {
            bfrag a[4], b[4];
            #pragma unroll
            for (int i = 0; i < 4; i++)
                a[i] = *(const bfrag*)&As[(wr * 64 + i * 16 + l15) * GLS + kk + l4 * 8];
            #pragma unroll
            for (int j = 0; j < 4; j++)
                b[j] = *(const bfrag*)&Bs[(wc * 64 + j * 16 + l15) * GLS + kk + l4 * 8];
            #pragma unroll
            for (int i = 0; i < 4; i++)
                #pragma unroll
                for (int j = 0; j < 4; j++)
                    acc[i][j] = __builtin_amdgcn_mfma_f32_16x16x32_bf16(a[i], b[j], acc[i][j], 0, 0, 0);
        }
        __syncthreads();
    }

    const int mat = n0 >> 8;                 // block-uniform (128 | 256)
    const int b   = m0 >> 11;                // block-uniform
    if (mat < 2) {
        ushort_t* dst = (mat == 0) ? Qb : Kb;
        #pragma unroll
        for (int j = 0; j < 4; j++) {
            const int n_glob = n0 + wc * 64 + j * 16 + l15;
            const int h = (n_glob >> 6) & 3;
            const int d = n_glob & 63;
            const float bj = bias[n_glob];
            const size_t rowbase = (size_t)((b * NH + h) * SEQ) * HD + d;
            #pragma unroll
            for (int i = 0; i < 4; i++) {
                const int t0 = (m0 & (SEQ - 1)) + wr * 64 + i * 16 + l4 * 4;
                #pragma unroll
                for (int r = 0; r < 4; r++)
                    dst[rowbase + (size_t)(t0 + r) * HD] = f2bf(acc[i][j][r] + bj);
            }
        }
    } else {
        // V: transpose through LDS, then coalesced stores of V^T rows.
        ushort_t (*T)[136] = (ushort_t(*)[136])smem;
        #pragma unroll
        for (int j = 0; j < 4; j++) {
            const int n_local = wc * 64 + j * 16 + l15;
            const float bj = bias[n0 + n_local];
            #pragma unroll
            for (int i = 0; i < 4; i++) {
                const int m_base = wr * 64 + i * 16 + l4 * 4;
                ushort4 pk;
                pk.x = f2bf(acc[i][j][0] + bj);
                pk.y = f2bf(acc[i][j][1] + bj);
                pk.z = f2bf(acc[i][j][2] + bj);
                pk.w = f2bf(acc[i][j][3] + bj);
                *(ushort4*)&T[n_local][m_base] = pk;
            }
        }
        __syncthreads();
        const int t0 = m0 & (SEQ - 1);
        #pragma unroll
        for (int rr = 0; rr < 8; rr++) {
            const int fid = tid + rr * 256;
            const int row = fid >> 4;            // n_local 0..127
            const int c8  = (fid & 15) * 8;      // m_local chunk
            const int n_glob = n0 + row;
            const int h = (n_glob >> 6) & 3;
            const int d = n_glob & 63;
            *(uint4*)&Vtb[(size_t)((b * NH + h) * HD + d) * SEQ + t0 + c8] =
                *(const uint4*)&T[row][c8];
        }
    }
}

// ---------------------------------------------------------------------------
// MFMA flash attention (causal) — unchanged from round 2 except bf16 output.
// ---------------------------------------------------------------------------
#define LS 72

__global__ __launch_bounds__(256) void attn_mfma_kernel(
    const ushort_t* __restrict__ Qb, const ushort_t* __restrict__ Kb,
    const ushort_t* __restrict__ Vtb, ushort_t* __restrict__ out) {
    __shared__ ushort_t Qs[64][LS];
    __shared__ ushort_t Ks[64][LS];
    __shared__ ushort_t Vts[64][LS];
    __shared__ ushort_t Ps[64][LS];

    const int tid = threadIdx.x;
    const int wv  = tid >> 6;
    const int ln  = tid & 63;
    const int l15 = ln & 15;
    const int l4  = ln >> 4;
    const int bh  = blockIdx.y;
    const int b   = bh >> 2;
    const int h   = bh & 3;

    for (int rep = 0; rep < 2; rep++) {
        const int qb = (rep == 0) ? (int)blockIdx.x : (NQB - 1 - (int)blockIdx.x);

        {
            const ushort_t* Qp = Qb + (size_t)(bh * SEQ + qb * 64) * HD;
            #pragma unroll
            for (int r = 0; r < 2; r++) {
                const int fid = tid + r * 256;
                const int row = fid >> 3, c8 = (fid & 7) * 8;
                *(uint4*)&Qs[row][c8] = *(const uint4*)&Qp[row * HD + c8];
            }
        }
        __syncthreads();
        const bfrag aq0 = *(const bfrag*)&Qs[wv * 16 + l15][l4 * 8];
        const bfrag aq1 = *(const bfrag*)&Qs[wv * 16 + l15][32 + l4 * 8];

        ffrag o[4];
        #pragma unroll
        for (int n = 0; n < 4; n++) o[n] = (ffrag){0.f, 0.f, 0.f, 0.f};
        float m_r[4] = {-INFINITY, -INFINITY, -INFINITY, -INFINITY};
        float l_r[4] = {0.f, 0.f, 0.f, 0.f};

        for (int kt = 0; kt <= qb; kt++) {
            {
                const ushort_t* Kp  = Kb  + (size_t)(bh * SEQ + kt * 64) * HD;
                const ushort_t* Vtp = Vtb + (size_t)(bh * HD) * SEQ + kt * 64;
                #pragma unroll
                for (int r = 0; r < 2; r++) {
                    const int fid = tid + r * 256;
                    const int row = fid >> 3, c8 = (fid & 7) * 8;
                    *(uint4*)&Ks[row][c8]  = *(const uint4*)&Kp[row * HD + c8];
                    *(uint4*)&Vts[row][c8] = *(const uint4*)&Vtp[row * SEQ + c8];
                }
            }
            __syncthreads();

            ffrag s[4];
            #pragma unroll
            for (int n = 0; n < 4; n++) {
                const bfrag bk0 = *(const bfrag*)&Ks[n * 16 + l15][l4 * 8];
                const bfrag bk1 = *(const bfrag*)&Ks[n * 16 + l15][32 + l4 * 8];
                ffrag z = (ffrag){0.f, 0.f, 0.f, 0.f};
                z = __builtin_amdgcn_mfma_f32_16x16x32_bf16(aq0, bk0, z, 0, 0, 0);
                z = __builtin_amdgcn_mfma_f32_16x16x32_bf16(aq1, bk1, z, 0, 0, 0);
                #pragma unroll
                for (int r = 0; r < 4; r++) z[r] *= SCALE;
                s[n] = z;
            }
            if (kt == qb) {
                #pragma unroll
                for (int n = 0; n < 4; n++)
                    #pragma unroll
                    for (int r = 0; r < 4; r++)
                        if (n * 16 + l15 > wv * 16 + l4 * 4 + r) s[n][r] = -INFINITY;
            }

            float alpha[4], rowsum[4] = {0.f, 0.f, 0.f, 0.f};
            #pragma unroll
            for (int r = 0; r < 4; r++) {
                float mx = fmaxf(fmaxf(s[0][r], s[1][r]), fmaxf(s[2][r], s[3][r]));
                #pragma unroll
                for (int off = 1; off < 16; off <<= 1)
                    mx = fmaxf(mx, __shfl_xor(mx, off));
                const float mo = m_r[r];
                const float mn = fmaxf(mo, mx);
                alpha[r] = __expf(mo - mn);
                m_r[r]   = mn;
            }
            #pragma unroll
            for (int n = 0; n < 4; n++)
                #pragma unroll
                for (int r = 0; r < 4; r++) {
                    const float p = __expf(s[n][r] - m_r[r]);
                    s[n][r] = p;
                    rowsum[r] += p;
                }
            #pragma unroll
            for (int r = 0; r < 4; r++) {
                float rs = rowsum[r];
                #pragma unroll
                for (int off = 1; off < 16; off <<= 1)
                    rs += __shfl_xor(rs, off);
                l_r[r] = l_r[r] * alpha[r] + rs;
            }
            #pragma unroll
            for (int n = 0; n < 4; n++)
                #pragma unroll
                for (int r = 0; r < 4; r++) o[n][r] *= alpha[r];

            #pragma unroll
            for (int n = 0; n < 4; n++)
                #pragma unroll
                for (int r = 0; r < 4; r++)
                    Ps[wv * 16 + l4 * 4 + r][n * 16 + l15] = f2bf(s[n][r]);
            const bfrag ap0 = *(const bfrag*)&Ps[wv * 16 + l15][l4 * 8];
            const bfrag ap1 = *(const bfrag*)&Ps[wv * 16 + l15][32 + l4 * 8];

            #pragma unroll
            for (int n = 0; n < 4; n++) {
                const bfrag bv0 = *(const bfrag*)&Vts[n * 16 + l15][l4 * 8];
                const bfrag bv1 = *(const bfrag*)&Vts[n * 16 + l15][32 + l4 * 8];
                o[n] = __builtin_amdgcn_mfma_f32_16x16x32_bf16(ap0, bv0, o[n], 0, 0, 0);
                o[n] = __builtin_amdgcn_mfma_f32_16x16x32_bf16(ap1, bv1, o[n], 0, 0, 0);
            }
            __syncthreads();
        }

        float linv[4];
        #pragma unroll
        for (int r = 0; r < 4; r++) linv[r] = 1.0f / l_r[r];
        const int tg = qb * 64 + wv * 16 + l4 * 4;
        ushort_t* op = out + (size_t)(b * SEQ) * CH + h * HD;
        #pragma unroll
        for (int n = 0; n < 4; n++)
            #pragma unroll
            for (int r = 0; r < 4; r++)
                op[(size_t)(tg + r) * CH + n * 16 + l15] = f2bf(o[n][r] * linv[r]);
    }
}

// ---------------------------------------------------------------------------
// Proj MFMA GEMM: attn_b(16384x256) @ WprojT^T + bproj -> fp32 out.
// Same 128x128 structure.
// ---------------------------------------------------------------------------
__global__ __launch_bounds__(256) void proj_mfma_kernel(
    const ushort_t* __restrict__ Ab, const ushort_t* __restrict__ Wt,
    const float* __restrict__ bias, float* __restrict__ O) {
    __shared__ ushort_t smem[2 * 128 * GLS];
    ushort_t* As = smem;
    ushort_t* Bs = smem + 128 * GLS;

    const int tid = threadIdx.x;
    const int wv  = tid >> 6;
    const int ln  = tid & 63;
    const int l15 = ln & 15;
    const int l4  = ln >> 4;
    const int wr  = wv >> 1;
    const int wc  = wv & 1;
    const int n0  = blockIdx.x * 128;
    const int m0  = blockIdx.y * 128;

    ffrag acc[4][4];
    #pragma unroll
    for (int i = 0; i < 4; i++)
        #pragma unroll
        for (int j = 0; j < 4; j++) acc[i][j] = (ffrag){0.f, 0.f, 0.f, 0.f};

    for (int k0 = 0; k0 < CH; k0 += 64) {
        #pragma unroll
        for (int r = 0; r < 4; r++) {
            const int fid = tid + r * 256;
            const int row = fid >> 3, c8 = (fid & 7) * 8;
            *(uint4*)&As[row * GLS + c8] = *(const uint4*)&Ab[(m0 + row) * CH + k0 + c8];
            *(uint4*)&Bs[row * GLS + c8] = *(const uint4*)&Wt[(n0 + row) * CH + k0 + c8];
        }
        __syncthreads();
        #pragma unroll
        for (int kk = 0; kk < 64; kk += 32) {
            bfrag a[4], b[4];
            #pragma unroll
            for (int i = 0; i < 4; i++)
                a[i] = *(const bfrag*)&As[(wr * 64 + i * 16 + l15) * GLS + kk + l4 * 8];
            #pragma unroll
            for (int j = 0; j < 4; j++)
                b[j] = *(const bfrag*)&Bs[(wc * 64 + j * 16 + l15) * GLS + kk + l4 * 8];
            #pragma unroll
            for (int i = 0; i < 4; i++)
                #pragma unroll
                for (int j = 0; j < 4; j++)
                    acc[i][j] = __builtin_amdgcn_mfma_f32_16x16x32_bf16(a[i], b[j], acc[i][j], 0, 0, 0);
        }
        __syncthreads();
    }

    #pragma unroll
    for (int j = 0; j < 4; j++) {
        const int n = n0 + wc * 64 + j * 16 + l15;
        const float bj = bias[n];
        #pragma unroll
        for (int i = 0; i < 4; i++) {
            const int m = m0 + wr * 64 + i * 16 + l4 * 4;
            #pragma unroll
            for (int r = 0; r < 4; r++)
                O[(size_t)(m + r) * CH + n] = acc[i][j][r] + bj;
        }
    }
}

extern "C" void kernel_launch(void* const* d_in, const int* in_sizes, int n_in,
                              void* d_out, int out_size, void* d_ws, size_t ws_size,
                              hipStream_t stream) {
    const float* x     = (const float*)d_in[0];
    const float* Wqkv  = (const float*)d_in[1];
    const float* bqkv  = (const float*)d_in[2];
    const float* Wproj = (const float*)d_in[3];
    const float* bproj = (const float*)d_in[4];
    float* out = (float*)d_out;

    const size_t BHTD = (size_t)BATCH * NH * SEQ * HD;   // 4,194,304
    ushort_t* xb     = (ushort_t*)d_ws;
    ushort_t* WqkvT  = xb + BHTD;                        // 768*256
    ushort_t* WprojT = WqkvT + (size_t)3 * CH * CH;      // 256*256
    ushort_t* Qb     = WprojT + (size_t)CH * CH;
    ushort_t* Kb     = Qb + BHTD;
    ushort_t* Vtb    = Kb + BHTD;
    ushort_t* attn_b = Vtb + BHTD;

    const int M = BATCH * SEQ;   // 16384

    // 0) Convert x -> bf16; transpose+convert weights.
    {
        const int total = XN + WQN + WPN;
        prep_kernel<<<(total + 255) / 256, 256, 0, stream>>>(x, Wqkv, Wproj, xb, WqkvT, WprojT);
    }
    // 1) QKV MFMA GEMM -> Q/K [BH,T,D], V^T [BH,D,T] (bf16)
    {
        dim3 grid((3 * CH) / 128, M / 128);
        qkv_mfma_kernel<<<grid, 256, 0, stream>>>(xb, WqkvT, bqkv, Qb, Kb, Vtb);
    }
    // 2) Causal MFMA flash attention -> bf16 [B,T,C]
    {
        dim3 grid(NQB / 2, BATCH * NH);
        attn_mfma_kernel<<<grid, 256, 0, stream>>>(Qb, Kb, Vtb, attn_b);
    }
    // 3) Output projection MFMA -> fp32 out
    {
        dim3 grid(CH / 128, M / 128);
        proj_mfma_kernel<<<grid, 256, 0, stream>>>(attn_b, WprojT, bproj, out);
    }
}

// Round 4
// 157.821 us; speedup vs baseline: 6.6234x; 1.1336x over previous
//
#include <hip/hip_runtime.h>
#include <hip/hip_bf16.h>
#include <math.h>

#define BATCH 8
#define SEQ   2048
#define CH    256
#define NH    4
#define HD    64
#define NQB   (SEQ / 64)      // 32 query tiles of 64
#define SCALE 0.125f          // 64^-0.5 (folded into Q at qkv epilogue)

typedef short  bfrag __attribute__((ext_vector_type(8)));  // 8 bf16 (4 VGPRs)
typedef float  ffrag __attribute__((ext_vector_type(4)));  // 4 fp32 acc
typedef unsigned short ushort_t;

__device__ __forceinline__ unsigned short f2bf(float f) {
    union { float f; unsigned int u; } v; v.f = f;
    unsigned int r = v.u + 0x7FFF + ((v.u >> 16) & 1);   // RNE
    return (unsigned short)(r >> 16);
}

// ---------------------------------------------------------------------------
// Prep: x -> bf16; Wqkv, Wproj -> transposed bf16 (W^T[n][k]).
// ---------------------------------------------------------------------------
#define XN  (BATCH * SEQ * CH / 4)   // 1048576 float4 groups
#define WQN (CH * 3 * CH)            // 196608
#define WPN (CH * CH)                // 65536

__global__ __launch_bounds__(256) void prep_kernel(
    const float* __restrict__ x, const float* __restrict__ Wqkv,
    const float* __restrict__ Wproj,
    ushort_t* __restrict__ xb, ushort_t* __restrict__ WqkvT,
    ushort_t* __restrict__ WprojT) {
    const int fid = blockIdx.x * 256 + threadIdx.x;
    if (fid < XN) {
        const float4 v = ((const float4*)x)[fid];
        ushort4 p;
        p.x = f2bf(v.x); p.y = f2bf(v.y); p.z = f2bf(v.z); p.w = f2bf(v.w);
        ((ushort4*)xb)[fid] = p;
    } else if (fid < XN + WQN) {
        const int i = fid - XN;
        const int n = i >> 8, k = i & 255;
        WqkvT[n * CH + k] = f2bf(Wqkv[k * (3 * CH) + n]);
    } else if (fid < XN + WQN + WPN) {
        const int i = fid - XN - WQN;
        const int n = i >> 8, k = i & 255;
        WprojT[n * CH + k] = f2bf(Wproj[k * CH + n]);
    }
}

// ---------------------------------------------------------------------------
// QKV MFMA GEMM: xb(16384x256) @ WqkvT^T + bqkv -> bf16 Q(*SCALE),K [BH,T,D],
// V^T [BH,D,T]. 128x128 block tile, 4 waves each 64x64, BK=64.
// ---------------------------------------------------------------------------
#define GLS 72   // LDS row stride in ushorts (144 B, 16B-aligned)

__global__ __launch_bounds__(256) void qkv_mfma_kernel(
    const ushort_t* __restrict__ xb, const ushort_t* __restrict__ Wt,
    const float* __restrict__ bias,
    ushort_t* __restrict__ Qb, ushort_t* __restrict__ Kb,
    ushort_t* __restrict__ Vtb) {
    __shared__ ushort_t smem[2 * 128 * GLS];   // As | Bs; reused as T[128][136]
    ushort_t* As = smem;
    ushort_t* Bs = smem + 128 * GLS;

    const int tid = threadIdx.x;
    const int wv  = tid >> 6;
    const int ln  = tid & 63;
    const int l15 = ln & 15;
    const int l4  = ln >> 4;
    const int wr  = wv >> 1;          // wave row 0..1
    const int wc  = wv & 1;           // wave col 0..1
    const int n0  = blockIdx.x * 128;
    const int m0  = blockIdx.y * 128;

    ffrag acc[4][4];
    #pragma unroll
    for (int i = 0; i < 4; i++)
        #pragma unroll
        for (int j = 0; j < 4; j++) acc[i][j] = (ffrag){0.f, 0.f, 0.f, 0.f};

    for (int k0 = 0; k0 < CH; k0 += 64) {
        #pragma unroll
        for (int r = 0; r < 4; r++) {
            const int fid = tid + r * 256;
            const int row = fid >> 3, c8 = (fid & 7) * 8;
            *(uint4*)&As[row * GLS + c8] = *(const uint4*)&xb[(m0 + row) * CH + k0 + c8];
            *(uint4*)&Bs[row * GLS + c8] = *(const uint4*)&Wt[(n0 + row) * CH + k0 + c8];
        }
        __syncthreads();
        #pragma unroll
        for (int kk = 0; kk < 64; kk += 32) {
            bfrag a[4], b[4];
            #pragma unroll
            for (int i = 0; i < 4; i++)
                a[i] = *(const bfrag*)&As[(wr * 64 + i * 16 + l15) * GLS + kk + l4 * 8];
            #pragma unroll
            for (int j = 0; j < 4; j++)
                b[j] = *(const bfrag*)&Bs[(wc * 64 + j * 16 + l15) * GLS + kk + l4 * 8];
            #pragma unroll
            for (int i = 0; i < 4; i++)
                #pragma unroll
                for (int j = 0; j < 4; j++)
                    acc[i][j] = __builtin_amdgcn_mfma_f32_16x16x32_bf16(a[i], b[j], acc[i][j], 0, 0, 0);
        }
        __syncthreads();
    }

    const int mat = n0 >> 8;                 // block-uniform
    const int b   = m0 >> 11;                // block-uniform
    if (mat < 2) {
        ushort_t* dst = (mat == 0) ? Qb : Kb;
        const float sc = (mat == 0) ? SCALE : 1.0f;
        #pragma unroll
        for (int j = 0; j < 4; j++) {
            const int n_glob = n0 + wc * 64 + j * 16 + l15;
            const int h = (n_glob >> 6) & 3;
            const int d = n_glob & 63;
            const float bj = bias[n_glob];
            const size_t rowbase = (size_t)((b * NH + h) * SEQ) * HD + d;
            #pragma unroll
            for (int i = 0; i < 4; i++) {
                const int t0 = (m0 & (SEQ - 1)) + wr * 64 + i * 16 + l4 * 4;
                #pragma unroll
                for (int r = 0; r < 4; r++)
                    dst[rowbase + (size_t)(t0 + r) * HD] = f2bf((acc[i][j][r] + bj) * sc);
            }
        }
    } else {
        // V: transpose through LDS, then coalesced stores of V^T rows.
        ushort_t (*T)[136] = (ushort_t(*)[136])smem;
        #pragma unroll
        for (int j = 0; j < 4; j++) {
            const int n_local = wc * 64 + j * 16 + l15;
            const float bj = bias[n0 + n_local];
            #pragma unroll
            for (int i = 0; i < 4; i++) {
                const int m_base = wr * 64 + i * 16 + l4 * 4;
                ushort4 pk;
                pk.x = f2bf(acc[i][j][0] + bj);
                pk.y = f2bf(acc[i][j][1] + bj);
                pk.z = f2bf(acc[i][j][2] + bj);
                pk.w = f2bf(acc[i][j][3] + bj);
                *(ushort4*)&T[n_local][m_base] = pk;
            }
        }
        __syncthreads();
        const int t0 = m0 & (SEQ - 1);
        #pragma unroll
        for (int rr = 0; rr < 8; rr++) {
            const int fid = tid + rr * 256;
            const int row = fid >> 4;            // n_local 0..127
            const int c8  = (fid & 15) * 8;      // m_local chunk
            const int n_glob = n0 + row;
            const int h = (n_glob >> 6) & 3;
            const int d = n_glob & 63;
            *(uint4*)&Vtb[(size_t)((b * NH + h) * HD + d) * SEQ + t0 + c8] =
                *(const uint4*)&T[row][c8];
        }
    }
}

// ---------------------------------------------------------------------------
// MFMA flash attention (causal), S^T formulation.
// S^T = K*Q^T: C-layout puts softmax dim (k) in regs+quads, q on lane&15.
// Per-q softmax state is a scalar; reductions are 15 in-reg ops + 2 shuffles.
// Grid: 1024 1D blocks; swizzle gives each CU qb-set {v,15-v,16+v,31-v}
// (uniform 66 iters/CU) and pins each bh's blocks to XCD bh%8 (L2 locality).
// ---------------------------------------------------------------------------
#define LS 72

__global__ __launch_bounds__(256) void attn_mfma_kernel(
    const ushort_t* __restrict__ Qb, const ushort_t* __restrict__ Kb,
    const ushort_t* __restrict__ Vtb, ushort_t* __restrict__ out) {
    __shared__ ushort_t Qs[64][LS];
    __shared__ ushort_t Ks[64][LS];
    __shared__ ushort_t Vts[64][LS];
    __shared__ ushort_t Ps[4][16][LS];   // per-wave private P (A-layout rows)
    __shared__ float aw[4][16];          // per-wave alpha broadcast
    __shared__ float lw[4][16];          // per-wave l broadcast

    const int tid = threadIdx.x;
    const int wv  = tid >> 6;
    const int ln  = tid & 63;
    const int l15 = ln & 15;
    const int l4  = ln >> 4;

    // block swizzle: perfect per-CU balance + per-bh XCD locality
    const int L  = blockIdx.x;
    const int g  = L & 255;
    const int s4 = L >> 8;               // 0..3
    const int v  = g >> 5;               // 0..7
    const int qb = (s4 == 0) ? v : (s4 == 1) ? (15 - v) : (s4 == 2) ? (16 + v) : (31 - v);
    const int bh = g & 31;
    const int b  = bh >> 2;
    const int h  = bh & 3;

    // ---- stage Q tile (64x64 bf16, pre-scaled by SCALE) ----
    {
        const ushort_t* Qp = Qb + (size_t)(bh * SEQ + qb * 64) * HD;
        #pragma unroll
        for (int r = 0; r < 2; r++) {
            const int fid = tid + r * 256;
            const int row = fid >> 3, c8 = (fid & 7) * 8;
            *(uint4*)&Qs[row][c8] = *(const uint4*)&Qp[row * HD + c8];
        }
    }
    __syncthreads();
    // Q as B-operand: B[n=q][k-chunk]
    const bfrag bq0 = *(const bfrag*)&Qs[wv * 16 + l15][l4 * 8];
    const bfrag bq1 = *(const bfrag*)&Qs[wv * 16 + l15][32 + l4 * 8];

    ffrag o[4];
    #pragma unroll
    for (int n = 0; n < 4; n++) o[n] = (ffrag){0.f, 0.f, 0.f, 0.f};
    float m_q = -INFINITY;   // per-q (q = wv*16+l15), replicated across quads
    float l_q = 0.f;

    const int qg_l = qb * 64 + wv * 16 + l15;   // this lane's q (global)

    for (int kt = 0; kt <= qb; kt++) {
        // ---- stage K tile + V^T tile ----
        {
            const ushort_t* Kp  = Kb  + (size_t)(bh * SEQ + kt * 64) * HD;
            const ushort_t* Vtp = Vtb + (size_t)(bh * HD) * SEQ + kt * 64;
            #pragma unroll
            for (int r = 0; r < 2; r++) {
                const int fid = tid + r * 256;
                const int row = fid >> 3, c8 = (fid & 7) * 8;
                *(uint4*)&Ks[row][c8]  = *(const uint4*)&Kp[row * HD + c8];
                *(uint4*)&Vts[row][c8] = *(const uint4*)&Vtp[row * SEQ + c8];
            }
        }
        __syncthreads();

        // ---- S^T = K Q^T : s[n][r] = S[q=l15][k = n*16 + l4*4 + r] ----
        ffrag s[4];
        #pragma unroll
        for (int n = 0; n < 4; n++) {
            const bfrag ak0 = *(const bfrag*)&Ks[n * 16 + l15][l4 * 8];
            const bfrag ak1 = *(const bfrag*)&Ks[n * 16 + l15][32 + l4 * 8];
            ffrag z = (ffrag){0.f, 0.f, 0.f, 0.f};
            z = __builtin_amdgcn_mfma_f32_16x16x32_bf16(ak0, bq0, z, 0, 0, 0);
            z = __builtin_amdgcn_mfma_f32_16x16x32_bf16(ak1, bq1, z, 0, 0, 0);
            s[n] = z;
        }
        if (kt == qb) {   // causal mask: k > q -> -inf
            #pragma unroll
            for (int n = 0; n < 4; n++)
                #pragma unroll
                for (int r = 0; r < 4; r++)
                    if (kt * 64 + n * 16 + l4 * 4 + r > qg_l) s[n][r] = -INFINITY;
        }

        // ---- online softmax: in-register max/sum + 2 quad shuffles ----
        float mx = s[0][0];
        #pragma unroll
        for (int n = 0; n < 4; n++)
            #pragma unroll
            for (int r = 0; r < 4; r++) mx = fmaxf(mx, s[n][r]);
        mx = fmaxf(mx, __shfl_xor(mx, 16));
        mx = fmaxf(mx, __shfl_xor(mx, 32));
        const float mo = m_q;
        const float mn = fmaxf(mo, mx);
        const float alpha = __expf(mo - mn);
        m_q = mn;

        float rs = 0.f;
        #pragma unroll
        for (int n = 0; n < 4; n++)
            #pragma unroll
            for (int r = 0; r < 4; r++) {
                const float p = __expf(s[n][r] - mn);
                s[n][r] = p;
                rs += p;
            }
        rs += __shfl_xor(rs, 16);
        rs += __shfl_xor(rs, 32);
        l_q = l_q * alpha + rs;

        // publish alpha for quad-indexed O-scale (per-wave, no barrier needed)
        if (l4 == 0) aw[wv][l15] = alpha;

        // ---- pack P into A-layout rows: Ps[wv][q=l15][k] (4x ds_write_b64) --
        #pragma unroll
        for (int n = 0; n < 4; n++) {
            const __hip_bfloat162 pa = __float22bfloat162_rn(make_float2(s[n][0], s[n][1]));
            const __hip_bfloat162 pb = __float22bfloat162_rn(make_float2(s[n][2], s[n][3]));
            uint2 pk;
            pk.x = *(const unsigned int*)&pa;
            pk.y = *(const unsigned int*)&pb;
            *(uint2*)&Ps[wv][l15][n * 16 + l4 * 4] = pk;
        }

        // O *= alpha (rows q = l4*4+r via LDS broadcast)
        const float4 al4 = *(const float4*)&aw[wv][l4 * 4];
        const float alr[4] = {al4.x, al4.y, al4.z, al4.w};
        #pragma unroll
        for (int n = 0; n < 4; n++)
            #pragma unroll
            for (int r = 0; r < 4; r++) o[n][r] *= alr[r];

        // ---- O += P @ V ----
        const bfrag ap0 = *(const bfrag*)&Ps[wv][l15][l4 * 8];
        const bfrag ap1 = *(const bfrag*)&Ps[wv][l15][32 + l4 * 8];
        #pragma unroll
        for (int n = 0; n < 4; n++) {
            const bfrag bv0 = *(const bfrag*)&Vts[n * 16 + l15][l4 * 8];
            const bfrag bv1 = *(const bfrag*)&Vts[n * 16 + l15][32 + l4 * 8];
            o[n] = __builtin_amdgcn_mfma_f32_16x16x32_bf16(ap0, bv0, o[n], 0, 0, 0);
            o[n] = __builtin_amdgcn_mfma_f32_16x16x32_bf16(ap1, bv1, o[n], 0, 0, 0);
        }
        __syncthreads();   // protect Ks/Vts before next staging
    }

    // ---- normalize + store O (bf16, [B,T,C]) ----
    if (l4 == 0) lw[wv][l15] = l_q;
    const float4 lv4 = *(const float4*)&lw[wv][l4 * 4];
    const float lvr[4] = {1.f / lv4.x, 1.f / lv4.y, 1.f / lv4.z, 1.f / lv4.w};
    const int tg = qb * 64 + wv * 16 + l4 * 4;
    ushort_t* op = out + (size_t)(b * SEQ) * CH + h * HD;
    #pragma unroll
    for (int n = 0; n < 4; n++)
        #pragma unroll
        for (int r = 0; r < 4; r++)
            op[(size_t)(tg + r) * CH + n * 16 + l15] = f2bf(o[n][r] * lvr[r]);
}

// ---------------------------------------------------------------------------
// Proj MFMA GEMM: attn_b(16384x256) @ WprojT^T + bproj -> fp32 out.
// ---------------------------------------------------------------------------
__global__ __launch_bounds__(256) void proj_mfma_kernel(
    const ushort_t* __restrict__ Ab, const ushort_t* __restrict__ Wt,
    const float* __restrict__ bias, float* __restrict__ O) {
    __shared__ ushort_t smem[2 * 128 * GLS];
    ushort_t* As = smem;
    ushort_t* Bs = smem + 128 * GLS;

    const int tid = threadIdx.x;
    const int wv  = tid >> 6;
    const int ln  = tid & 63;
    const int l15 = ln & 15;
    const int l4  = ln >> 4;
    const int wr  = wv >> 1;
    const int wc  = wv & 1;
    const int n0  = blockIdx.x * 128;
    const int m0  = blockIdx.y * 128;

    ffrag acc[4][4];
    #pragma unroll
    for (int i = 0; i < 4; i++)
        #pragma unroll
        for (int j = 0; j < 4; j++) acc[i][j] = (ffrag){0.f, 0.f, 0.f, 0.f};

    for (int k0 = 0; k0 < CH; k0 += 64) {
        #pragma unroll
        for (int r = 0; r < 4; r++) {
            const int fid = tid + r * 256;
            const int row = fid >> 3, c8 = (fid & 7) * 8;
            *(uint4*)&As[row * GLS + c8] = *(const uint4*)&Ab[(m0 + row) * CH + k0 + c8];
            *(uint4*)&Bs[row * GLS + c8] = *(const uint4*)&Wt[(n0 + row) * CH + k0 + c8];
        }
        __syncthreads();
        #pragma unroll
        for (int kk = 0; kk < 64; kk += 32) {
            bfrag a[4], b[4];
            #pragma unroll
            for (int i = 0; i < 4; i++)
                a[i] = *(const bfrag*)&As[(wr * 64 + i * 16 + l15) * GLS + kk + l4 * 8];
            #pragma unroll
            for (int j = 0; j < 4; j++)
                b[j] = *(const bfrag*)&Bs[(wc * 64 + j * 16 + l15) * GLS + kk + l4 * 8];
            #pragma unroll
            for (int i = 0; i < 4; i++)
                #pragma unroll
                for (int j = 0; j < 4; j++)
                    acc[i][j] = __builtin_amdgcn_mfma_f32_16x16x32_bf16(a[i], b[j], acc[i][j], 0, 0, 0);
        }
        __syncthreads();
    }

    #pragma unroll
    for (int j = 0; j < 4; j++) {
        const int n = n0 + wc * 64 + j * 16 + l15;
        const float bj = bias[n];
        #pragma unroll
        for (int i = 0; i < 4; i++) {
            const int m = m0 + wr * 64 + i * 16 + l4 * 4;
            #pragma unroll
            for (int r = 0; r < 4; r++)
                O[(size_t)(m + r) * CH + n] = acc[i][j][r] + bj;
        }
    }
}

extern "C" void kernel_launch(void* const* d_in, const int* in_sizes, int n_in,
                              void* d_out, int out_size, void* d_ws, size_t ws_size,
                              hipStream_t stream) {
    const float* x     = (const float*)d_in[0];
    const float* Wqkv  = (const float*)d_in[1];
    const float* bqkv  = (const float*)d_in[2];
    const float* Wproj = (const float*)d_in[3];
    const float* bproj = (const float*)d_in[4];
    float* out = (float*)d_out;

    const size_t BHTD = (size_t)BATCH * NH * SEQ * HD;   // 4,194,304
    ushort_t* xb     = (ushort_t*)d_ws;
    ushort_t* WqkvT  = xb + BHTD;
    ushort_t* WprojT = WqkvT + (size_t)3 * CH * CH;
    ushort_t* Qb     = WprojT + (size_t)CH * CH;
    ushort_t* Kb     = Qb + BHTD;
    ushort_t* Vtb    = Kb + BHTD;
    ushort_t* attn_b = Vtb + BHTD;

    const int M = BATCH * SEQ;   // 16384

    {
        const int total = XN + WQN + WPN;
        prep_kernel<<<(total + 255) / 256, 256, 0, stream>>>(x, Wqkv, Wproj, xb, WqkvT, WprojT);
    }
    {
        dim3 grid((3 * CH) / 128, M / 128);
        qkv_mfma_kernel<<<grid, 256, 0, stream>>>(xb, WqkvT, bqkv, Qb, Kb, Vtb);
    }
    {
        attn_mfma_kernel<<<dim3(NQB * BATCH * NH), 256, 0, stream>>>(Qb, Kb, Vtb, attn_b);
    }
    {
        dim3 grid(CH / 128, M / 128);
        proj_mfma_kernel<<<grid, 256, 0, stream>>>(attn_b, WprojT, bproj, out);
    }
}

// Round 5
// 145.427 us; speedup vs baseline: 7.1879x; 1.0852x over previous
//
#include <hip/hip_runtime.h>
#include <hip/hip_bf16.h>
#include <math.h>

#define BATCH 8
#define SEQ   2048
#define CH    256
#define NH    4
#define HD    64
#define NQB   (SEQ / 64)      // 32 query tiles of 64
// Q pre-scale: 64^-0.5 * log2(e)  (softmax runs in exp2 domain)
#define QSCALE 0.18033688011112042f

typedef short  bfrag __attribute__((ext_vector_type(8)));  // 8 bf16 (4 VGPRs)
typedef float  ffrag __attribute__((ext_vector_type(4)));  // 4 fp32 acc
typedef unsigned short ushort_t;

__device__ __forceinline__ unsigned short f2bf(float f) {
    union { float f; unsigned int u; } v; v.f = f;
    unsigned int r = v.u + 0x7FFF + ((v.u >> 16) & 1);   // RNE
    return (unsigned short)(r >> 16);
}

// ---------------------------------------------------------------------------
// Prep: x -> bf16; Wqkv, Wproj -> transposed bf16 (W^T[n][k]).
// ---------------------------------------------------------------------------
#define XN  (BATCH * SEQ * CH / 4)   // 1048576 float4 groups
#define WQN (CH * 3 * CH)            // 196608
#define WPN (CH * CH)                // 65536

__global__ __launch_bounds__(256) void prep_kernel(
    const float* __restrict__ x, const float* __restrict__ Wqkv,
    const float* __restrict__ Wproj,
    ushort_t* __restrict__ xb, ushort_t* __restrict__ WqkvT,
    ushort_t* __restrict__ WprojT) {
    const int fid = blockIdx.x * 256 + threadIdx.x;
    if (fid < XN) {
        const float4 v = ((const float4*)x)[fid];
        ushort4 p;
        p.x = f2bf(v.x); p.y = f2bf(v.y); p.z = f2bf(v.z); p.w = f2bf(v.w);
        ((ushort4*)xb)[fid] = p;
    } else if (fid < XN + WQN) {
        const int i = fid - XN;
        const int n = i >> 8, k = i & 255;
        WqkvT[n * CH + k] = f2bf(Wqkv[k * (3 * CH) + n]);
    } else if (fid < XN + WQN + WPN) {
        const int i = fid - XN - WQN;
        const int n = i >> 8, k = i & 255;
        WprojT[n * CH + k] = f2bf(Wproj[k * CH + n]);
    }
}

// ---------------------------------------------------------------------------
// QKV MFMA GEMM: xb(16384x256) @ WqkvT^T + bqkv -> bf16 Q(*QSCALE),K [BH,T,D],
// V^T [BH,D,T]. 128x128 block tile, 4 waves each 64x64, BK=64.
// All three epilogues transpose through LDS -> coalesced 16B global stores.
// ---------------------------------------------------------------------------
#define GLS 72   // LDS row stride in ushorts (144 B, 16B-aligned)

__global__ __launch_bounds__(256) void qkv_mfma_kernel(
    const ushort_t* __restrict__ xb, const ushort_t* __restrict__ Wt,
    const float* __restrict__ bias,
    ushort_t* __restrict__ Qb, ushort_t* __restrict__ Kb,
    ushort_t* __restrict__ Vtb) {
    __shared__ ushort_t smem[2 * 128 * GLS];   // As | Bs; reused as T[128][136]
    ushort_t* As = smem;
    ushort_t* Bs = smem + 128 * GLS;

    const int tid = threadIdx.x;
    const int wv  = tid >> 6;
    const int ln  = tid & 63;
    const int l15 = ln & 15;
    const int l4  = ln >> 4;
    const int wr  = wv >> 1;          // wave row 0..1
    const int wc  = wv & 1;           // wave col 0..1
    const int n0  = blockIdx.x * 128;
    const int m0  = blockIdx.y * 128;

    ffrag acc[4][4];
    #pragma unroll
    for (int i = 0; i < 4; i++)
        #pragma unroll
        for (int j = 0; j < 4; j++) acc[i][j] = (ffrag){0.f, 0.f, 0.f, 0.f};

    for (int k0 = 0; k0 < CH; k0 += 64) {
        #pragma unroll
        for (int r = 0; r < 4; r++) {
            const int fid = tid + r * 256;
            const int row = fid >> 3, c8 = (fid & 7) * 8;
            *(uint4*)&As[row * GLS + c8] = *(const uint4*)&xb[(m0 + row) * CH + k0 + c8];
            *(uint4*)&Bs[row * GLS + c8] = *(const uint4*)&Wt[(n0 + row) * CH + k0 + c8];
        }
        __syncthreads();
        #pragma unroll
        for (int kk = 0; kk < 64; kk += 32) {
            bfrag a[4], b[4];
            #pragma unroll
            for (int i = 0; i < 4; i++)
                a[i] = *(const bfrag*)&As[(wr * 64 + i * 16 + l15) * GLS + kk + l4 * 8];
            #pragma unroll
            for (int j = 0; j < 4; j++)
                b[j] = *(const bfrag*)&Bs[(wc * 64 + j * 16 + l15) * GLS + kk + l4 * 8];
            #pragma unroll
            for (int i = 0; i < 4; i++)
                #pragma unroll
                for (int j = 0; j < 4; j++)
                    acc[i][j] = __builtin_amdgcn_mfma_f32_16x16x32_bf16(a[i], b[j], acc[i][j], 0, 0, 0);
        }
        __syncthreads();
    }

    const int mat = n0 >> 8;                 // block-uniform: 0=Q 1=K 2=V
    const int b   = m0 >> 11;                // block-uniform
    const int t0  = m0 & (SEQ - 1);
    ushort_t (*T)[136] = (ushort_t(*)[136])smem;

    if (mat < 2) {
        // Q/K: transpose to T[t_local][n_local], then coalesced [T,D] stores.
        const float sc = (mat == 0) ? QSCALE : 1.0f;
        #pragma unroll
        for (int j = 0; j < 4; j++) {
            const int n_local = wc * 64 + j * 16 + l15;
            const float bj = bias[n0 + n_local];
            #pragma unroll
            for (int i = 0; i < 4; i++) {
                const int m_base = wr * 64 + i * 16 + l4 * 4;
                #pragma unroll
                for (int r = 0; r < 4; r++)
                    T[m_base + r][n_local] = f2bf((acc[i][j][r] + bj) * sc);
            }
        }
        __syncthreads();
        ushort_t* dst = (mat == 0) ? Qb : Kb;
        #pragma unroll
        for (int rr = 0; rr < 8; rr++) {
            const int fid = tid + rr * 256;
            const int row = fid >> 4;            // t_local 0..127
            const int c8  = (fid & 15) * 8;      // n_local chunk (within one head)
            const int n_glob = n0 + c8;
            const int h = (n_glob >> 6) & 3;
            const int d = n_glob & 63;
            *(uint4*)&dst[((size_t)((b * NH + h) * SEQ) + t0 + row) * HD + d] =
                *(const uint4*)&T[row][c8];
        }
    } else {
        // V: transpose to T[n_local][m_local], then coalesced [D,T] stores.
        #pragma unroll
        for (int j = 0; j < 4; j++) {
            const int n_local = wc * 64 + j * 16 + l15;
            const float bj = bias[n0 + n_local];
            #pragma unroll
            for (int i = 0; i < 4; i++) {
                const int m_base = wr * 64 + i * 16 + l4 * 4;
                ushort4 pk;
                pk.x = f2bf(acc[i][j][0] + bj);
                pk.y = f2bf(acc[i][j][1] + bj);
                pk.z = f2bf(acc[i][j][2] + bj);
                pk.w = f2bf(acc[i][j][3] + bj);
                *(ushort4*)&T[n_local][m_base] = pk;
            }
        }
        __syncthreads();
        #pragma unroll
        for (int rr = 0; rr < 8; rr++) {
            const int fid = tid + rr * 256;
            const int row = fid >> 4;            // n_local 0..127
            const int c8  = (fid & 15) * 8;      // m_local chunk
            const int n_glob = n0 + row;
            const int h = (n_glob >> 6) & 3;
            const int d = n_glob & 63;
            *(uint4*)&Vtb[(size_t)((b * NH + h) * HD + d) * SEQ + t0 + c8] =
                *(const uint4*)&T[row][c8];
        }
    }
}

// ---------------------------------------------------------------------------
// MFMA flash attention (causal), S^T formulation, exp2-domain softmax.
// - K/V tile kt+1 prefetched into VGPRs during compute of tile kt (latency
//   hidden across the compute phase; drained harmlessly at the end barrier).
// - Ps aliased onto Qs (Q frags live in registers) -> 28.2 KB LDS, 5 blk/CU.
// - Longest q-tiles dispatch first; per-CU slot set {v,15-v,16+v,31-v} = 66
//   iters; bh = g&31 pins each head's blocks to one XCD (L2 locality).
// ---------------------------------------------------------------------------
#define LSA 72

__global__ __launch_bounds__(256, 5) void attn_mfma_kernel(
    const ushort_t* __restrict__ Qb, const ushort_t* __restrict__ Kb,
    const ushort_t* __restrict__ Vtb, ushort_t* __restrict__ out) {
    __shared__ ushort_t Qs[64][LSA];   // Q tile; reused as P (A-layout) in-loop
    __shared__ ushort_t Ks[64][LSA];
    __shared__ ushort_t Vts[64][LSA];
    __shared__ float aw[4][16];        // per-wave alpha broadcast
    __shared__ float lw[4][16];        // per-wave l broadcast

    const int tid = threadIdx.x;
    const int wv  = tid >> 6;
    const int ln  = tid & 63;
    const int l15 = ln & 15;
    const int l4  = ln >> 4;

    const int L  = blockIdx.x;
    const int g  = L & 255;
    const int s4 = L >> 8;               // 0..3 (dispatch wave)
    const int v  = g >> 5;               // 0..7
    // longest-first: 31-v, 16+v, 15-v, v  (same per-CU set, sum of iters = 66)
    const int qb = (s4 == 0) ? (31 - v) : (s4 == 1) ? (16 + v) : (s4 == 2) ? (15 - v) : v;
    const int bh = g & 31;
    const int b  = bh >> 2;
    const int h  = bh & 3;

    // ---- stage Q tile (64x64 bf16, pre-scaled by QSCALE) ----
    {
        const ushort_t* Qp = Qb + (size_t)(bh * SEQ + qb * 64) * HD;
        #pragma unroll
        for (int r = 0; r < 2; r++) {
            const int fid = tid + r * 256;
            const int row = fid >> 3, c8 = (fid & 7) * 8;
            *(uint4*)&Qs[row][c8] = *(const uint4*)&Qp[row * HD + c8];
        }
    }

    // ---- preload K/V tile 0 into registers ----
    const ushort_t* Kbase = Kb  + (size_t)bh * SEQ * HD;
    const ushort_t* Vbase = Vtb + (size_t)bh * HD * SEQ;
    const int srow = (tid + 0) >> 3,  sc8a = ((tid + 0) & 7) * 8;
    const int srow2 = (tid + 256) >> 3, sc8b = ((tid + 256) & 7) * 8;
    uint4 kK0, kK1, kV0, kV1;
    kK0 = *(const uint4*)&Kbase[srow  * HD + sc8a];
    kK1 = *(const uint4*)&Kbase[srow2 * HD + sc8b];
    kV0 = *(const uint4*)&Vbase[srow  * SEQ + sc8a];
    kV1 = *(const uint4*)&Vbase[srow2 * SEQ + sc8b];

    __syncthreads();
    // Q as B-operand: B[n=q][k]  (q = wv*16+l15)
    const bfrag bq0 = *(const bfrag*)&Qs[wv * 16 + l15][l4 * 8];
    const bfrag bq1 = *(const bfrag*)&Qs[wv * 16 + l15][32 + l4 * 8];

    ffrag o[4];
    #pragma unroll
    for (int n = 0; n < 4; n++) o[n] = (ffrag){0.f, 0.f, 0.f, 0.f};
    float m_q = -INFINITY;   // log2-domain running max (replicated across quads)
    float l_q = 0.f;

    const int qg_l = qb * 64 + wv * 16 + l15;   // this lane's q (global)

    for (int kt = 0; kt <= qb; kt++) {
        // ---- commit prefetched tile to LDS ----
        *(uint4*)&Ks[srow][sc8a]   = kK0;
        *(uint4*)&Ks[srow2][sc8b]  = kK1;
        *(uint4*)&Vts[srow][sc8a]  = kV0;
        *(uint4*)&Vts[srow2][sc8b] = kV1;
        __syncthreads();

        // ---- issue prefetch for tile kt+1 (lands during compute) ----
        if (kt < qb) {
            const ushort_t* Kp  = Kbase + (size_t)(kt + 1) * 64 * HD;
            const ushort_t* Vtp = Vbase + (kt + 1) * 64;
            kK0 = *(const uint4*)&Kp[srow  * HD + sc8a];
            kK1 = *(const uint4*)&Kp[srow2 * HD + sc8b];
            kV0 = *(const uint4*)&Vtp[srow  * SEQ + sc8a];
            kV1 = *(const uint4*)&Vtp[srow2 * SEQ + sc8b];
        }

        // ---- S^T = K Q^T : s[n][r] = S[q=l15][k = n*16 + l4*4 + r] ----
        ffrag s[4];
        #pragma unroll
        for (int n = 0; n < 4; n++) {
            const bfrag ak0 = *(const bfrag*)&Ks[n * 16 + l15][l4 * 8];
            const bfrag ak1 = *(const bfrag*)&Ks[n * 16 + l15][32 + l4 * 8];
            ffrag z = (ffrag){0.f, 0.f, 0.f, 0.f};
            z = __builtin_amdgcn_mfma_f32_16x16x32_bf16(ak0, bq0, z, 0, 0, 0);
            z = __builtin_amdgcn_mfma_f32_16x16x32_bf16(ak1, bq1, z, 0, 0, 0);
            s[n] = z;
        }
        if (kt == qb) {   // causal mask: k > q -> -inf
            #pragma unroll
            for (int n = 0; n < 4; n++)
                #pragma unroll
                for (int r = 0; r < 4; r++)
                    if (kt * 64 + n * 16 + l4 * 4 + r > qg_l) s[n][r] = -INFINITY;
        }

        // ---- online softmax (exp2 domain): in-reg reduce + 2 quad shuffles --
        float mx = s[0][0];
        #pragma unroll
        for (int n = 0; n < 4; n++)
            #pragma unroll
            for (int r = 0; r < 4; r++) mx = fmaxf(mx, s[n][r]);
        mx = fmaxf(mx, __shfl_xor(mx, 16));
        mx = fmaxf(mx, __shfl_xor(mx, 32));
        const float mo = m_q;
        const float mn = fmaxf(mo, mx);
        const float alpha = __builtin_amdgcn_exp2f(mo - mn);
        m_q = mn;

        float rs = 0.f;
        #pragma unroll
        for (int n = 0; n < 4; n++)
            #pragma unroll
            for (int r = 0; r < 4; r++) {
                const float p = __builtin_amdgcn_exp2f(s[n][r] - mn);
                s[n][r] = p;
                rs += p;
            }
        rs += __shfl_xor(rs, 16);
        rs += __shfl_xor(rs, 32);
        l_q = l_q * alpha + rs;

        if (l4 == 0) aw[wv][l15] = alpha;

        // ---- pack P into A-layout rows aliased onto Qs (per-wave private) --
        #pragma unroll
        for (int n = 0; n < 4; n++) {
            const __hip_bfloat162 pa = __float22bfloat162_rn(make_float2(s[n][0], s[n][1]));
            const __hip_bfloat162 pb = __float22bfloat162_rn(make_float2(s[n][2], s[n][3]));
            uint2 pk;
            pk.x = *(const unsigned int*)&pa;
            pk.y = *(const unsigned int*)&pb;
            *(uint2*)&Qs[wv * 16 + l15][n * 16 + l4 * 4] = pk;
        }

        // O *= alpha (rows q = l4*4+r via per-wave LDS broadcast)
        const float4 al4 = *(const float4*)&aw[wv][l4 * 4];
        const float alr[4] = {al4.x, al4.y, al4.z, al4.w};
        #pragma unroll
        for (int n = 0; n < 4; n++)
            #pragma unroll
            for (int r = 0; r < 4; r++) o[n][r] *= alr[r];

        // ---- O += P @ V ----
        const bfrag ap0 = *(const bfrag*)&Qs[wv * 16 + l15][l4 * 8];
        const bfrag ap1 = *(const bfrag*)&Qs[wv * 16 + l15][32 + l4 * 8];
        #pragma unroll
        for (int n = 0; n < 4; n++) {
            const bfrag bv0 = *(const bfrag*)&Vts[n * 16 + l15][l4 * 8];
            const bfrag bv1 = *(const bfrag*)&Vts[n * 16 + l15][32 + l4 * 8];
            o[n] = __builtin_amdgcn_mfma_f32_16x16x32_bf16(ap0, bv0, o[n], 0, 0, 0);
            o[n] = __builtin_amdgcn_mfma_f32_16x16x32_bf16(ap1, bv1, o[n], 0, 0, 0);
        }
        __syncthreads();   // consumers done -> LDS free (also drains prefetch)
    }

    // ---- normalize + store O (bf16, [B,T,C]) ----
    if (l4 == 0) lw[wv][l15] = l_q;
    const float4 lv4 = *(const float4*)&lw[wv][l4 * 4];
    const float lvr[4] = {1.f / lv4.x, 1.f / lv4.y, 1.f / lv4.z, 1.f / lv4.w};
    const int tg = qb * 64 + wv * 16 + l4 * 4;
    ushort_t* op = out + (size_t)(b * SEQ) * CH + h * HD;
    #pragma unroll
    for (int n = 0; n < 4; n++)
        #pragma unroll
        for (int r = 0; r < 4; r++)
            op[(size_t)(tg + r) * CH + n * 16 + l15] = f2bf(o[n][r] * lvr[r]);
}

// ---------------------------------------------------------------------------
// Proj MFMA GEMM: attn_b(16384x256) @ WprojT^T + bproj -> fp32 out.
// ---------------------------------------------------------------------------
__global__ __launch_bounds__(256) void proj_mfma_kernel(
    const ushort_t* __restrict__ Ab, const ushort_t* __restrict__ Wt,
    const float* __restrict__ bias, float* __restrict__ O) {
    __shared__ ushort_t smem[2 * 128 * GLS];
    ushort_t* As = smem;
    ushort_t* Bs = smem + 128 * GLS;

    const int tid = threadIdx.x;
    const int wv  = tid >> 6;
    const int ln  = tid & 63;
    const int l15 = ln & 15;
    const int l4  = ln >> 4;
    const int wr  = wv >> 1;
    const int wc  = wv & 1;
    const int n0  = blockIdx.x * 128;
    const int m0  = blockIdx.y * 128;

    ffrag acc[4][4];
    #pragma unroll
    for (int i = 0; i < 4; i++)
        #pragma unroll
        for (int j = 0; j < 4; j++) acc[i][j] = (ffrag){0.f, 0.f, 0.f, 0.f};

    for (int k0 = 0; k0 < CH; k0 += 64) {
        #pragma unroll
        for (int r = 0; r < 4; r++) {
            const int fid = tid + r * 256;
            const int row = fid >> 3, c8 = (fid & 7) * 8;
            *(uint4*)&As[row * GLS + c8] = *(const uint4*)&Ab[(m0 + row) * CH + k0 + c8];
            *(uint4*)&Bs[row * GLS + c8] = *(const uint4*)&Wt[(n0 + row) * CH + k0 + c8];
        }
        __syncthreads();
        #pragma unroll
        for (int kk = 0; kk < 64; kk += 32) {
            bfrag a[4], b[4];
            #pragma unroll
            for (int i = 0; i < 4; i++)
                a[i] = *(const bfrag*)&As[(wr * 64 + i * 16 + l15) * GLS + kk + l4 * 8];
            #pragma unroll
            for (int j = 0; j < 4; j++)
                b[j] = *(const bfrag*)&Bs[(wc * 64 + j * 16 + l15) * GLS + kk + l4 * 8];
            #pragma unroll
            for (int i = 0; i < 4; i++)
                #pragma unroll
                for (int j = 0; j < 4; j++)
                    acc[i][j] = __builtin_amdgcn_mfma_f32_16x16x32_bf16(a[i], b[j], acc[i][j], 0, 0, 0);
        }
        __syncthreads();
    }

    #pragma unroll
    for (int j = 0; j < 4; j++) {
        const int n = n0 + wc * 64 + j * 16 + l15;
        const float bj = bias[n];
        #pragma unroll
        for (int i = 0; i < 4; i++) {
            const int m = m0 + wr * 64 + i * 16 + l4 * 4;
            #pragma unroll
            for (int r = 0; r < 4; r++)
                O[(size_t)(m + r) * CH + n] = acc[i][j][r] + bj;
        }
    }
}

extern "C" void kernel_launch(void* const* d_in, const int* in_sizes, int n_in,
                              void* d_out, int out_size, void* d_ws, size_t ws_size,
                              hipStream_t stream) {
    const float* x     = (const float*)d_in[0];
    const float* Wqkv  = (const float*)d_in[1];
    const float* bqkv  = (const float*)d_in[2];
    const float* Wproj = (const float*)d_in[3];
    const float* bproj = (const float*)d_in[4];
    float* out = (float*)d_out;

    const size_t BHTD = (size_t)BATCH * NH * SEQ * HD;   // 4,194,304
    ushort_t* xb     = (ushort_t*)d_ws;
    ushort_t* WqkvT  = xb + BHTD;
    ushort_t* WprojT = WqkvT + (size_t)3 * CH * CH;
    ushort_t* Qb     = WprojT + (size_t)CH * CH;
    ushort_t* Kb     = Qb + BHTD;
    ushort_t* Vtb    = Kb + BHTD;
    ushort_t* attn_b = Vtb + BHTD;

    const int M = BATCH * SEQ;   // 16384

    {
        const int total = XN + WQN + WPN;
        prep_kernel<<<(total + 255) / 256, 256, 0, stream>>>(x, Wqkv, Wproj, xb, WqkvT, WprojT);
    }
    {
        dim3 grid((3 * CH) / 128, M / 128);
        qkv_mfma_kernel<<<grid, 256, 0, stream>>>(xb, WqkvT, bqkv, Qb, Kb, Vtb);
    }
    {
        attn_mfma_kernel<<<dim3(NQB * BATCH * NH), 256, 0, stream>>>(Qb, Kb, Vtb, attn_b);
    }
    {
        dim3 grid(CH / 128, M / 128);
        proj_mfma_kernel<<<grid, 256, 0, stream>>>(attn_b, WprojT, bproj, out);
    }
}

// Round 6
// 144.152 us; speedup vs baseline: 7.2514x; 1.0088x over previous
//
#include <hip/hip_runtime.h>
#include <hip/hip_bf16.h>
#include <math.h>

#define BATCH 8
#define SEQ   2048
#define CH    256
#define NH    4
#define HD    64
#define NQB   (SEQ / 64)      // 32 query tiles of 64
// Q pre-scale: 64^-0.5 * log2(e)  (softmax runs in exp2 domain)
#define QSCALE 0.18033688011112042f

typedef short  bfrag __attribute__((ext_vector_type(8)));  // 8 bf16 (4 VGPRs)
typedef float  ffrag __attribute__((ext_vector_type(4)));  // 4 fp32 acc
typedef unsigned short ushort_t;

__device__ __forceinline__ unsigned short f2bf(float f) {
    union { float f; unsigned int u; } v; v.f = f;
    unsigned int r = v.u + 0x7FFF + ((v.u >> 16) & 1);   // RNE
    return (unsigned short)(r >> 16);
}
__device__ __forceinline__ unsigned int pack2(float a, float b) {
    const __hip_bfloat162 p = __float22bfloat162_rn(make_float2(a, b));
    return *(const unsigned int*)&p;
}

// ---------------------------------------------------------------------------
// Prep (weights only): Wqkv, Wproj -> transposed bf16 (W^T[n][k]).
// ---------------------------------------------------------------------------
#define WQN (CH * 3 * CH)            // 196608
#define WPN (CH * CH)                // 65536

__global__ __launch_bounds__(256) void prep_kernel(
    const float* __restrict__ Wqkv, const float* __restrict__ Wproj,
    ushort_t* __restrict__ WqkvT, ushort_t* __restrict__ WprojT) {
    const int fid = blockIdx.x * 256 + threadIdx.x;
    if (fid < WQN) {
        const int n = fid >> 8, k = fid & 255;
        WqkvT[n * CH + k] = f2bf(Wqkv[k * (3 * CH) + n]);
    } else if (fid < WQN + WPN) {
        const int i = fid - WQN;
        const int n = i >> 8, k = i & 255;
        WprojT[n * CH + k] = f2bf(Wproj[k * CH + n]);
    }
}

// ---------------------------------------------------------------------------
// QKV MFMA GEMM: x fp32 (16384x256) @ WqkvT^T + bqkv -> bf16 Q(*QSCALE),K
// [BH,T,D], V^T [BH,D,T]. 128x128 tile, 4 waves each 64x64, BK=64.
// x converted fp32->bf16 during LDS staging (no separate conversion pass).
// ---------------------------------------------------------------------------
#define GLS 72   // LDS row stride in ushorts (144 B, 16B-aligned)

__global__ __launch_bounds__(256) void qkv_mfma_kernel(
    const float* __restrict__ x, const ushort_t* __restrict__ Wt,
    const float* __restrict__ bias,
    ushort_t* __restrict__ Qb, ushort_t* __restrict__ Kb,
    ushort_t* __restrict__ Vtb) {
    __shared__ ushort_t smem[2 * 128 * GLS];   // As | Bs; reused as T[128][136]
    ushort_t* As = smem;
    ushort_t* Bs = smem + 128 * GLS;

    const int tid = threadIdx.x;
    const int wv  = tid >> 6;
    const int ln  = tid & 63;
    const int l15 = ln & 15;
    const int l4  = ln >> 4;
    const int wr  = wv >> 1;          // wave row 0..1
    const int wc  = wv & 1;           // wave col 0..1
    const int n0  = blockIdx.x * 128;
    const int m0  = blockIdx.y * 128;

    ffrag acc[4][4];
    #pragma unroll
    for (int i = 0; i < 4; i++)
        #pragma unroll
        for (int j = 0; j < 4; j++) acc[i][j] = (ffrag){0.f, 0.f, 0.f, 0.f};

    for (int k0 = 0; k0 < CH; k0 += 64) {
        #pragma unroll
        for (int r = 0; r < 4; r++) {
            const int fid = tid + r * 256;
            const int row = fid >> 3, c8 = (fid & 7) * 8;
            // A: read 8 fp32 of x, convert to bf16 on the fly
            const float* xp = &x[(size_t)(m0 + row) * CH + k0 + c8];
            const float4 va = *(const float4*)xp;
            const float4 vb = *(const float4*)(xp + 4);
            uint4 pk;
            pk.x = pack2(va.x, va.y); pk.y = pack2(va.z, va.w);
            pk.z = pack2(vb.x, vb.y); pk.w = pack2(vb.z, vb.w);
            *(uint4*)&As[row * GLS + c8] = pk;
            *(uint4*)&Bs[row * GLS + c8] = *(const uint4*)&Wt[(n0 + row) * CH + k0 + c8];
        }
        __syncthreads();
        #pragma unroll
        for (int kk = 0; kk < 64; kk += 32) {
            bfrag a[4], b[4];
            #pragma unroll
            for (int i = 0; i < 4; i++)
                a[i] = *(const bfrag*)&As[(wr * 64 + i * 16 + l15) * GLS + kk + l4 * 8];
            #pragma unroll
            for (int j = 0; j < 4; j++)
                b[j] = *(const bfrag*)&Bs[(wc * 64 + j * 16 + l15) * GLS + kk + l4 * 8];
            #pragma unroll
            for (int i = 0; i < 4; i++)
                #pragma unroll
                for (int j = 0; j < 4; j++)
                    acc[i][j] = __builtin_amdgcn_mfma_f32_16x16x32_bf16(a[i], b[j], acc[i][j], 0, 0, 0);
        }
        __syncthreads();
    }

    const int mat = n0 >> 8;                 // block-uniform: 0=Q 1=K 2=V
    const int b   = m0 >> 11;                // block-uniform
    const int t0  = m0 & (SEQ - 1);
    ushort_t (*T)[136] = (ushort_t(*)[136])smem;

    if (mat < 2) {
        // Q/K: transpose to T[t_local][n_local], then coalesced [T,D] stores.
        const float sc = (mat == 0) ? QSCALE : 1.0f;
        #pragma unroll
        for (int j = 0; j < 4; j++) {
            const int n_local = wc * 64 + j * 16 + l15;
            const float bj = bias[n0 + n_local];
            #pragma unroll
            for (int i = 0; i < 4; i++) {
                const int m_base = wr * 64 + i * 16 + l4 * 4;
                #pragma unroll
                for (int r = 0; r < 4; r++)
                    T[m_base + r][n_local] = f2bf((acc[i][j][r] + bj) * sc);
            }
        }
        __syncthreads();
        ushort_t* dst = (mat == 0) ? Qb : Kb;
        #pragma unroll
        for (int rr = 0; rr < 8; rr++) {
            const int fid = tid + rr * 256;
            const int row = fid >> 4;            // t_local 0..127
            const int c8  = (fid & 15) * 8;      // n_local chunk
            const int n_glob = n0 + c8;
            const int h = (n_glob >> 6) & 3;
            const int d = n_glob & 63;
            *(uint4*)&dst[((size_t)((b * NH + h) * SEQ) + t0 + row) * HD + d] =
                *(const uint4*)&T[row][c8];
        }
    } else {
        // V: transpose to T[n_local][m_local], then coalesced [D,T] stores.
        #pragma unroll
        for (int j = 0; j < 4; j++) {
            const int n_local = wc * 64 + j * 16 + l15;
            const float bj = bias[n0 + n_local];
            #pragma unroll
            for (int i = 0; i < 4; i++) {
                const int m_base = wr * 64 + i * 16 + l4 * 4;
                ushort4 pk;
                pk.x = f2bf(acc[i][j][0] + bj);
                pk.y = f2bf(acc[i][j][1] + bj);
                pk.z = f2bf(acc[i][j][2] + bj);
                pk.w = f2bf(acc[i][j][3] + bj);
                *(ushort4*)&T[n_local][m_base] = pk;
            }
        }
        __syncthreads();
        #pragma unroll
        for (int rr = 0; rr < 8; rr++) {
            const int fid = tid + rr * 256;
            const int row = fid >> 4;            // n_local 0..127
            const int c8  = (fid & 15) * 8;      // m_local chunk
            const int n_glob = n0 + row;
            const int h = (n_glob >> 6) & 3;
            const int d = n_glob & 63;
            *(uint4*)&Vtb[(size_t)((b * NH + h) * HD + d) * SEQ + t0 + c8] =
                *(const uint4*)&T[row][c8];
        }
    }
}

// ---------------------------------------------------------------------------
// MFMA flash attention (causal), S^T formulation, exp2 softmax.
// Round-6 structure:
//  - double-buffered K/V in LDS: ONE barrier per K-tile iteration
//  - register prefetch one full iteration ahead of the LDS commit
//  - unpadded 64-ushort rows + XOR-16B-chunk swizzle (conflict-free)
//  - LDS exactly 40 KB -> 4 blocks/CU; Q frags loaded direct from global
//  - alpha / l broadcast via __shfl (no LDS arrays)
// ---------------------------------------------------------------------------
__global__ __launch_bounds__(256, 4) void attn_mfma_kernel(
    const ushort_t* __restrict__ Qb, const ushort_t* __restrict__ Kb,
    const ushort_t* __restrict__ Vtb, ushort_t* __restrict__ out) {
    __shared__ ushort_t Ps[64 * 64];       // P tiles (wave-private 16-row bands)
    __shared__ ushort_t KV[4 * 64 * 64];   // K0 | K1 | V0 | V1 (8 KB each)

    const int tid = threadIdx.x;
    const int wv  = tid >> 6;
    const int ln  = tid & 63;
    const int l15 = ln & 15;
    const int l4  = ln >> 4;
    const int e   = l15 & 7;

    const int L  = blockIdx.x;
    const int g  = L & 255;
    const int s4 = L >> 8;               // dispatch wave 0..3
    const int v  = g >> 5;               // 0..7
    // longest-first; per-CU slot set {31-v, 16+v, 15-v, v} sums to 66 iters
    const int qb = (s4 == 0) ? (31 - v) : (s4 == 1) ? (16 + v) : (s4 == 2) ? (15 - v) : v;
    const int bh = g & 31;
    const int b  = bh >> 2;
    const int h  = bh & 3;

    // ---- Q fragments straight from global (B-operand: B[n=q][k]) ----
    const ushort_t* Qp = Qb + ((size_t)(bh * SEQ + qb * 64 + wv * 16 + l15)) * HD + l4 * 8;
    const bfrag bq0 = *(const bfrag*)Qp;
    const bfrag bq1 = *(const bfrag*)(Qp + 32);

    // ---- staging geometry ----
    const ushort_t* Kbase = Kb  + (size_t)bh * SEQ * HD;
    const ushort_t* Vbase = Vtb + (size_t)bh * HD * SEQ;
    const int srow  = tid >> 3;            // 0..31
    const int sc    = tid & 7;             // logical 16B-chunk
    const int goffA = srow * 64 + sc * 8;              // K global (ushorts)
    const int voffA = srow * SEQ + sc * 8;             // V global
    const int soffA = srow * 64 + ((sc ^ (srow & 7)) * 8);   // swizzled LDS
    // second slot: rows +32 (same low-3 row bits -> same swizzle term)
    // goffB = goffA + 32*64 ; voffB = voffA + 32*SEQ ; soffB = soffA + 2048

    // ---- fragment read offsets (precomputed, swizzled) ----
    const int kf0 = l15 * 64 + ((l4 ^ e) * 8);   // + n*1024 ; ^32 for k-chunk 1
    const int pf0 = (wv * 16 + l15) * 64 + ((l4 ^ e) * 8);
    // P write: base + ((n ^ pp) << 4)
    const int pp = e >> 1;
    const int pwb = (wv * 16 + l15) * 64 + (((l4 >> 1) ^ (e & 1)) * 8) + (l4 & 1) * 4;

    // ---- prologue: tile 0 -> regs -> LDS buf0 ; tile 1 -> regs ----
    uint4 kK0, kK1, kV0, kV1;
    kK0 = *(const uint4*)&Kbase[goffA];
    kK1 = *(const uint4*)&Kbase[goffA + 32 * 64];
    kV0 = *(const uint4*)&Vbase[voffA];
    kV1 = *(const uint4*)&Vbase[voffA + 32 * SEQ];
    *(uint4*)&KV[soffA]          = kK0;
    *(uint4*)&KV[soffA + 2048]   = kK1;
    *(uint4*)&KV[8192 + soffA]        = kV0;
    *(uint4*)&KV[8192 + soffA + 2048] = kV1;
    if (qb >= 1) {
        kK0 = *(const uint4*)&Kbase[4096 + goffA];
        kK1 = *(const uint4*)&Kbase[4096 + goffA + 32 * 64];
        kV0 = *(const uint4*)&Vbase[64 + voffA];
        kV1 = *(const uint4*)&Vbase[64 + voffA + 32 * SEQ];
    }

    ffrag o[4];
    #pragma unroll
    for (int n = 0; n < 4; n++) o[n] = (ffrag){0.f, 0.f, 0.f, 0.f};
    float m_q = -INFINITY;
    float l_q = 0.f;
    const int qg_l = qb * 64 + wv * 16 + l15;

    for (int kt = 0; kt <= qb; kt++) {
        if (kt > 0) {
            // commit prefetched tile kt into buffer kt&1
            const int kb = (kt & 1) * 4096;
            *(uint4*)&KV[kb + soffA]          = kK0;
            *(uint4*)&KV[kb + soffA + 2048]   = kK1;
            *(uint4*)&KV[8192 + kb + soffA]        = kV0;
            *(uint4*)&KV[8192 + kb + soffA + 2048] = kV1;
            if (kt < qb) {   // issue loads for tile kt+1 (land during compute)
                const ushort_t* Kp  = Kbase + (kt + 1) * 4096;
                const ushort_t* Vtp = Vbase + (kt + 1) * 64;
                kK0 = *(const uint4*)&Kp[goffA];
                kK1 = *(const uint4*)&Kp[goffA + 32 * 64];
                kV0 = *(const uint4*)&Vtp[voffA];
                kV1 = *(const uint4*)&Vtp[voffA + 32 * SEQ];
            }
        }
        __syncthreads();   // the ONLY barrier in the iteration

        const ushort_t* Kbuf = KV + (kt & 1) * 4096;
        const ushort_t* Vbuf = KV + 8192 + (kt & 1) * 4096;

        // ---- S^T = K Q^T : s[n][r] = S[q=l15][k = n*16 + l4*4 + r] ----
        ffrag s[4];
        #pragma unroll
        for (int n = 0; n < 4; n++) {
            const bfrag ak0 = *(const bfrag*)&Kbuf[n * 1024 + kf0];
            const bfrag ak1 = *(const bfrag*)&Kbuf[n * 1024 + (kf0 ^ 32)];
            ffrag z = (ffrag){0.f, 0.f, 0.f, 0.f};
            z = __builtin_amdgcn_mfma_f32_16x16x32_bf16(ak0, bq0, z, 0, 0, 0);
            z = __builtin_amdgcn_mfma_f32_16x16x32_bf16(ak1, bq1, z, 0, 0, 0);
            s[n] = z;
        }
        if (kt == qb) {   // causal mask on the diagonal tile
            #pragma unroll
            for (int n = 0; n < 4; n++)
                #pragma unroll
                for (int r = 0; r < 4; r++)
                    if (kt * 64 + n * 16 + l4 * 4 + r > qg_l) s[n][r] = -INFINITY;
        }

        // ---- online softmax (exp2 domain) ----
        float mx = s[0][0];
        #pragma unroll
        for (int n = 0; n < 4; n++)
            #pragma unroll
            for (int r = 0; r < 4; r++) mx = fmaxf(mx, s[n][r]);
        mx = fmaxf(mx, __shfl_xor(mx, 16));
        mx = fmaxf(mx, __shfl_xor(mx, 32));
        const float mn = fmaxf(m_q, mx);
        const float alpha = __builtin_amdgcn_exp2f(m_q - mn);
        m_q = mn;

        float rs = 0.f;
        #pragma unroll
        for (int n = 0; n < 4; n++)
            #pragma unroll
            for (int r = 0; r < 4; r++) {
                const float p = __builtin_amdgcn_exp2f(s[n][r] - mn);
                s[n][r] = p;
                rs += p;
            }
        rs += __shfl_xor(rs, 16);
        rs += __shfl_xor(rs, 32);
        l_q = l_q * alpha + rs;

        // ---- pack P (bf16, A-layout, swizzled, wave-private rows) ----
        #pragma unroll
        for (int n = 0; n < 4; n++) {
            uint2 pk;
            pk.x = pack2(s[n][0], s[n][1]);
            pk.y = pack2(s[n][2], s[n][3]);
            *(uint2*)&Ps[pwb + ((n ^ pp) << 4)] = pk;
        }

        // ---- O *= alpha (row l4*4+r alpha via shuffle) ----
        #pragma unroll
        for (int r = 0; r < 4; r++) {
            const float ar = __shfl(alpha, l4 * 20 + r);
            #pragma unroll
            for (int n = 0; n < 4; n++) o[n][r] *= ar;
        }

        // ---- O += P @ V ----
        const bfrag ap0 = *(const bfrag*)&Ps[pf0];
        const bfrag ap1 = *(const bfrag*)&Ps[pf0 ^ 32];
        #pragma unroll
        for (int n = 0; n < 4; n++) {
            const bfrag bv0 = *(const bfrag*)&Vbuf[n * 1024 + kf0];
            const bfrag bv1 = *(const bfrag*)&Vbuf[n * 1024 + (kf0 ^ 32)];
            o[n] = __builtin_amdgcn_mfma_f32_16x16x32_bf16(ap0, bv0, o[n], 0, 0, 0);
            o[n] = __builtin_amdgcn_mfma_f32_16x16x32_bf16(ap1, bv1, o[n], 0, 0, 0);
        }
    }

    // ---- normalize + store O (bf16, [B,T,C]) ----
    const int tg = qb * 64 + wv * 16 + l4 * 4;
    ushort_t* op = out + (size_t)(b * SEQ) * CH + h * HD;
    #pragma unroll
    for (int r = 0; r < 4; r++) {
        const float lr = __shfl(l_q, l4 * 20 + r);
        const float li = 1.0f / lr;
        #pragma unroll
        for (int n = 0; n < 4; n++)
            op[(size_t)(tg + r) * CH + n * 16 + l15] = f2bf(o[n][r] * li);
    }
}

// ---------------------------------------------------------------------------
// Proj MFMA GEMM: attn_b(16384x256) @ WprojT^T + bproj -> fp32 out.
// 128x64 tile (4 waves: 2x2, each 64x32), grid 512 -> 2 blocks/CU.
// ---------------------------------------------------------------------------
__global__ __launch_bounds__(256) void proj_mfma_kernel(
    const ushort_t* __restrict__ Ab, const ushort_t* __restrict__ Wt,
    const float* __restrict__ bias, float* __restrict__ O) {
    __shared__ ushort_t smem[(128 + 64) * GLS];
    ushort_t* As = smem;
    ushort_t* Bs = smem + 128 * GLS;

    const int tid = threadIdx.x;
    const int wv  = tid >> 6;
    const int ln  = tid & 63;
    const int l15 = ln & 15;
    const int l4  = ln >> 4;
    const int wr  = wv >> 1;          // 0..1 -> 64-row band
    const int wc  = wv & 1;           // 0..1 -> 32-col band
    const int n0  = blockIdx.x * 64;
    const int m0  = blockIdx.y * 128;

    ffrag acc[4][2];
    #pragma unroll
    for (int i = 0; i < 4; i++)
        #pragma unroll
        for (int j = 0; j < 2; j++) acc[i][j] = (ffrag){0.f, 0.f, 0.f, 0.f};

    for (int k0 = 0; k0 < CH; k0 += 64) {
        #pragma unroll
        for (int r = 0; r < 4; r++) {   // A: 128x64 = 1024 chunks
            const int fid = tid + r * 256;
            const int row = fid >> 3, c8 = (fid & 7) * 8;
            *(uint4*)&As[row * GLS + c8] = *(const uint4*)&Ab[(size_t)(m0 + row) * CH + k0 + c8];
        }
        #pragma unroll
        for (int r = 0; r < 2; r++) {   // B: 64x64 = 512 chunks
            const int fid = tid + r * 256;
            const int row = fid >> 3, c8 = (fid & 7) * 8;
            *(uint4*)&Bs[row * GLS + c8] = *(const uint4*)&Wt[(n0 + row) * CH + k0 + c8];
        }
        __syncthreads();
        #pragma unroll
        for (int kk = 0; kk < 64; kk += 32) {
            bfrag a[4], b[2];
            #pragma unroll
            for (int i = 0; i < 4; i++)
                a[i] = *(const bfrag*)&As[(wr * 64 + i * 16 + l15) * GLS + kk + l4 * 8];
            #pragma unroll
            for (int j = 0; j < 2; j++)
                b[j] = *(const bfrag*)&Bs[(wc * 32 + j * 16 + l15) * GLS + kk + l4 * 8];
            #pragma unroll
            for (int i = 0; i < 4; i++)
                #pragma unroll
                for (int j = 0; j < 2; j++)
                    acc[i][j] = __builtin_amdgcn_mfma_f32_16x16x32_bf16(a[i], b[j], acc[i][j], 0, 0, 0);
        }
        __syncthreads();
    }

    #pragma unroll
    for (int j = 0; j < 2; j++) {
        const int n = n0 + wc * 32 + j * 16 + l15;
        const float bj = bias[n];
        #pragma unroll
        for (int i = 0; i < 4; i++) {
            const int m = m0 + wr * 64 + i * 16 + l4 * 4;
            #pragma unroll
            for (int r = 0; r < 4; r++)
                O[(size_t)(m + r) * CH + n] = acc[i][j][r] + bj;
        }
    }
}

extern "C" void kernel_launch(void* const* d_in, const int* in_sizes, int n_in,
                              void* d_out, int out_size, void* d_ws, size_t ws_size,
                              hipStream_t stream) {
    const float* x     = (const float*)d_in[0];
    const float* Wqkv  = (const float*)d_in[1];
    const float* bqkv  = (const float*)d_in[2];
    const float* Wproj = (const float*)d_in[3];
    const float* bproj = (const float*)d_in[4];
    float* out = (float*)d_out;

    const size_t BHTD = (size_t)BATCH * NH * SEQ * HD;   // 4,194,304
    ushort_t* WqkvT  = (ushort_t*)d_ws;
    ushort_t* WprojT = WqkvT + (size_t)3 * CH * CH;
    ushort_t* Qb     = WprojT + (size_t)CH * CH;
    ushort_t* Kb     = Qb + BHTD;
    ushort_t* Vtb    = Kb + BHTD;
    ushort_t* attn_b = Vtb + BHTD;

    const int M = BATCH * SEQ;   // 16384

    {
        const int total = WQN + WPN;
        prep_kernel<<<(total + 255) / 256, 256, 0, stream>>>(Wqkv, Wproj, WqkvT, WprojT);
    }
    {
        dim3 grid((3 * CH) / 128, M / 128);
        qkv_mfma_kernel<<<grid, 256, 0, stream>>>(x, WqkvT, bqkv, Qb, Kb, Vtb);
    }
    {
        attn_mfma_kernel<<<dim3(NQB * BATCH * NH), 256, 0, stream>>>(Qb, Kb, Vtb, attn_b);
    }
    {
        dim3 grid(CH / 64, M / 128);
        proj_mfma_kernel<<<grid, 256, 0, stream>>>(attn_b, WprojT, bproj, out);
    }
}